// Round 2
// baseline (490.124 us; speedup 1.0000x reference)
//
#include <hip/hip_runtime.h>
#include <hip/hip_bf16.h>
#include <cstdint>
#include <cstddef>

typedef short s16x8 __attribute__((ext_vector_type(8)));
typedef float f32x4 __attribute__((ext_vector_type(4)));

#define AVG_LOG_F 2.8332133f  // ln(17)

static __device__ __forceinline__ float b2f(unsigned short u) {
  union { unsigned int i; float f; } x; x.i = ((unsigned int)u) << 16; return x.f;
}
static __device__ __forceinline__ unsigned short f2b(float f) {
  __hip_bfloat16 h = __float2bfloat16(f);
  union { __hip_bfloat16 hh; unsigned short u; } c; c.hh = h; return c.u;
}
static __device__ __forceinline__ unsigned int pack2(float lo, float hi) {
  return (unsigned int)f2b(lo) | ((unsigned int)f2b(hi) << 16);
}

// ---------- h fp32 -> bf16 (4 floats / thread) ----------
__global__ void conv_h_kernel(const float* __restrict__ h, unsigned short* __restrict__ hb, int total4) {
  int i = blockIdx.x * blockDim.x + threadIdx.x;
  if (i >= total4) return;
  const float4 v = ((const float4*)h)[i];
  uint2 r;
  r.x = pack2(v.x, v.y);
  r.y = pack2(v.z, v.w);
  ((uint2*)hb)[i] = r;
}

// ---------- WcatT[c][k]: c<128 -> W_pre[k][c] (dst half), else W_pre[128+k][c-128] (src half) ----------
__global__ void fold_wcat_kernel(const float* __restrict__ W_pre, unsigned short* __restrict__ WcatT) {
  int idx = blockIdx.x * blockDim.x + threadIdx.x;  // 256*128 total
  int c = idx >> 7, k = idx & 127;
  float v = (c < 128) ? W_pre[k * 128 + c] : W_pre[(128 + k) * 128 + (c - 128)];
  WcatT[c * 128 + k] = f2b(v);
}

// ---------- WfoldT[j][i] = sum_k W_post[i][k]*W_lin[k][j]; block 1664 computes bfold ----------
__global__ void fold_wpost_kernel(const float* __restrict__ W_post, const float* __restrict__ b_post,
                                  const float* __restrict__ W_lin, const float* __restrict__ b_lin,
                                  unsigned short* __restrict__ WfoldT, float* __restrict__ bfold) {
  const int j = threadIdx.x;
  const int i = blockIdx.x;
  if (i == 1664) {
    float acc = b_lin[j];
    for (int k = 0; k < 128; ++k) acc += b_post[k] * W_lin[k * 128 + j];
    bfold[j] = acc;
  } else {
    float acc = 0.f;
    for (int k = 0; k < 128; ++k) acc += W_post[i * 128 + k] * W_lin[k * 128 + j];
    WfoldT[(size_t)j * 1664 + i] = f2b(acc);
  }
}

// ---------- CSR build ----------
__global__ void hist_kernel(const int* __restrict__ dst, int* __restrict__ cnt, int E) {
  const int e = blockIdx.x * blockDim.x + threadIdx.x;
  if (e < E) atomicAdd(&cnt[dst[e]], 1);
}

__global__ void scan_kernel(const int* __restrict__ cnt, int* __restrict__ rowptr,
                            int* __restrict__ cursor, int n) {
  __shared__ int shm[1024];
  const int tid = threadIdx.x;
  const int CH = (n + 1023) >> 10;
  const int lo = tid * CH;
  const int hi = min(lo + CH, n);
  int sum = 0;
  for (int i = lo; i < hi; ++i) sum += cnt[i];
  shm[tid] = sum;
  __syncthreads();
  for (int offt = 1; offt < 1024; offt <<= 1) {
    int t = (tid >= offt) ? shm[tid - offt] : 0;
    __syncthreads();
    shm[tid] += t;
    __syncthreads();
  }
  int run = shm[tid] - sum;  // exclusive prefix of this chunk
  for (int i = lo; i < hi; ++i) {
    rowptr[i] = run; cursor[i] = run; run += cnt[i];
  }
  if (tid == 1023) rowptr[n] = shm[1023];
}

__global__ void scatter_kernel(const int* __restrict__ src, const int* __restrict__ dst,
                               int* __restrict__ cursor, int* __restrict__ ssrc, int E) {
  const int e = blockIdx.x * blockDim.x + threadIdx.x;
  if (e < E) {
    const int d = dst[e];
    const int p = atomicAdd(&cursor[d], 1);
    ssrc[p] = src[e];
  }
}

// ---------- GEMM 1: AB[M,256] = hb[M,128] @ WcatT[256,128]^T, bf16 out ----------
__global__ __launch_bounds__(256) void gemm256_kernel(
    const unsigned short* __restrict__ A, const unsigned short* __restrict__ BT,
    unsigned short* __restrict__ outb, int M)
{
  constexpr int LDT = 40;  // 32 + 8 pad: max 2-way LDS aliasing (free per m136)
  constexpr int K = 128, NK = K / 32;
  __shared__ alignas(16) unsigned short Asm[2][128 * LDT];
  __shared__ alignas(16) unsigned short Bsm[2][128 * LDT];
  const int tid = threadIdx.x, lane = tid & 63;
  const int w = tid >> 6, wr = w >> 1, wc = w & 1;
  const int row0 = blockIdx.x * 128;
  const int col0 = blockIdx.y * 128;
  const int srow = tid >> 2, slot = tid & 3;
  const int ar0 = min(row0 + srow, M - 1);
  const int ar1 = min(row0 + srow + 64, M - 1);
  const unsigned short* ap0 = A + (size_t)ar0 * K + slot * 8;
  const unsigned short* ap1 = A + (size_t)ar1 * K + slot * 8;
  const unsigned short* bp0 = BT + (size_t)(col0 + srow) * K + slot * 8;
  const unsigned short* bp1 = BT + (size_t)(col0 + srow + 64) * K + slot * 8;
  const int wa0 = srow * LDT + slot * 8, wa1 = wa0 + 64 * LDT;

  int offA[4], offB[4];
#pragma unroll
  for (int i = 0; i < 4; ++i) {
    offA[i] = (wr * 64 + i * 16 + (lane & 15)) * LDT + (lane >> 4) * 8;
    offB[i] = (wc * 64 + i * 16 + (lane & 15)) * LDT + (lane >> 4) * 8;
  }

  f32x4 acc[4][4] = {};
  uint4 a0 = *(const uint4*)ap0;
  uint4 a1 = *(const uint4*)ap1;
  uint4 b0 = *(const uint4*)bp0;
  uint4 b1 = *(const uint4*)bp1;
  *(uint4*)&Asm[0][wa0] = a0; *(uint4*)&Asm[0][wa1] = a1;
  *(uint4*)&Bsm[0][wa0] = b0; *(uint4*)&Bsm[0][wa1] = b1;
  __syncthreads();

  for (int kt = 0; kt < NK; ++kt) {
    const int cur = kt & 1;
    if (kt + 1 < NK) {
      const int k0 = (kt + 1) * 32;
      a0 = *(const uint4*)(ap0 + k0); a1 = *(const uint4*)(ap1 + k0);
      b0 = *(const uint4*)(bp0 + k0); b1 = *(const uint4*)(bp1 + k0);
    }
    s16x8 af[4], bq[4];
#pragma unroll
    for (int i = 0; i < 4; ++i) af[i] = *(const s16x8*)&Asm[cur][offA[i]];
#pragma unroll
    for (int i = 0; i < 4; ++i) bq[i] = *(const s16x8*)&Bsm[cur][offB[i]];
#pragma unroll
    for (int mi = 0; mi < 4; ++mi)
#pragma unroll
      for (int ni = 0; ni < 4; ++ni)
        acc[mi][ni] = __builtin_amdgcn_mfma_f32_16x16x32_bf16(af[mi], bq[ni], acc[mi][ni], 0, 0, 0);
    if (kt + 1 < NK) {
      const int nxt = cur ^ 1;
      *(uint4*)&Asm[nxt][wa0] = a0; *(uint4*)&Asm[nxt][wa1] = a1;
      *(uint4*)&Bsm[nxt][wa0] = b0; *(uint4*)&Bsm[nxt][wa1] = b1;
      __syncthreads();
    }
  }

#pragma unroll
  for (int mi = 0; mi < 4; ++mi) {
#pragma unroll
    for (int ni = 0; ni < 4; ++ni) {
      const int rbase = row0 + wr * 64 + mi * 16 + (lane >> 4) * 4;
      const int c = col0 + wc * 64 + ni * 16 + (lane & 15);
#pragma unroll
      for (int r = 0; r < 4; ++r) {
        const int rr = rbase + r;
        if (rr < M) outb[(size_t)rr * 256 + c] = f2b(acc[mi][ni][r]);
      }
    }
  }
}

// ---------- per-node aggregation: one wave per node, 2 feature cols per lane ----------
__global__ void aggregate_kernel(const unsigned short* __restrict__ AB,
                                 const unsigned short* __restrict__ hb,
                                 const float* __restrict__ b_pre,
                                 const int* __restrict__ rowptr, const int* __restrict__ ssrc,
                                 unsigned short* __restrict__ Xagg,
                                 float* __restrict__ sc1, float* __restrict__ sc2, int n) {
  const int node = blockIdx.x * 4 + (threadIdx.x >> 6);
  if (node >= n) return;
  const int lane = threadIdx.x & 63;
  const int beg = rowptr[node], end = rowptr[node + 1];
  const int cnt = end - beg;
  float s0 = 0.f, s1v = 0.f, q0 = 0.f, q1 = 0.f;
  float mn0 = 3.4e38f, mn1 = 3.4e38f, mx0 = -3.4e38f, mx1 = -3.4e38f;
  for (int base = beg; base < end; base += 64) {
    const int mcnt = min(64, end - base);
    const int myidx = (base + lane < end) ? ssrc[base + lane] : 0;
#pragma unroll 4
    for (int t = 0; t < mcnt; ++t) {
      const int sidx = __shfl(myidx, t);
      const unsigned int v = *(const unsigned int*)(AB + (size_t)sidx * 256 + 128 + 2 * lane);
      const float v0 = b2f((unsigned short)(v & 0xffffu));
      const float v1 = b2f((unsigned short)(v >> 16));
      s0 += v0; q0 += v0 * v0; mn0 = fminf(mn0, v0); mx0 = fmaxf(mx0, v0);
      s1v += v1; q1 += v1 * v1; mn1 = fminf(mn1, v1); mx1 = fmaxf(mx1, v1);
    }
  }
  const float degf = (float)(cnt > 0 ? cnt : 1);
  const float2 bp = ((const float2*)b_pre)[lane];
  const unsigned int cpair = *(const unsigned int*)(AB + (size_t)node * 256 + 2 * lane);
  const float c0 = b2f((unsigned short)(cpair & 0xffffu)) + bp.x;
  const float c1 = b2f((unsigned short)(cpair >> 16)) + bp.y;
  float mean0, mean1, std0, std1, lo0, lo1, hi0, hi1;
  if (cnt > 0) {
    const float inv = 1.f / degf;
    const float mu0 = s0 * inv, mu1 = s1v * inv;
    mean0 = c0 + mu0; mean1 = c1 + mu1;
    std0 = sqrtf(fmaxf(q0 * inv - mu0 * mu0, 0.f) + 1e-5f);
    std1 = sqrtf(fmaxf(q1 * inv - mu1 * mu1, 0.f) + 1e-5f);
    lo0 = c0 + mn0; lo1 = c1 + mn1; hi0 = c0 + mx0; hi1 = c1 + mx1;
  } else {
    mean0 = mean1 = lo0 = lo1 = hi0 = hi1 = 0.f;
    std0 = std1 = sqrtf(1e-5f);
  }
  const float logd = logf(degf + 1.f);
  unsigned int* row = (unsigned int*)(Xagg + (size_t)node * 640);
  row[lane]       = *(const unsigned int*)(hb + (size_t)node * 128 + 2 * lane);
  row[64 + lane]  = pack2(mean0, mean1);
  row[128 + lane] = pack2(lo0, lo1);
  row[192 + lane] = pack2(hi0, hi1);
  row[256 + lane] = pack2(std0, std1);
  if (lane == 0) { sc1[node] = logd / AVG_LOG_F; sc2[node] = AVG_LOG_F / logd; }
}

// ---------- GEMM 2: out3[M,128] = X13[M,1664] @ WfoldT[128,1664]^T + bfold, ----------
// ---------- X13 synthesized at staging: k<640 -> Xagg[k]; k<1152 -> Xagg[k-512]*s1; else Xagg[k-1024]*s2 ----------
static __device__ __forceinline__ uint4 scale8(uint4 r, float s) {
  union { uint4 v; unsigned short h[8]; } in, out;
  in.v = r;
#pragma unroll
  for (int i = 0; i < 8; ++i) out.h[i] = f2b(b2f(in.h[i]) * s);
  return out.v;
}
static __device__ __forceinline__ uint4 loadA_fold(const unsigned short* base, int kc,
                                                   float s1v, float s2v) {
  const bool m1 = kc >= 640;
  const bool m2 = kc >= 1152;
  const int off = kc - (m1 ? 512 : 0) - (m2 ? 512 : 0);
  uint4 r = *(const uint4*)(base + off);
  if (m1) r = scale8(r, m2 ? s2v : s1v);
  return r;
}

__global__ __launch_bounds__(256) void gemm_fold_kernel(
    const unsigned short* __restrict__ Xagg, const float* __restrict__ sc1,
    const float* __restrict__ sc2, const unsigned short* __restrict__ WT,
    const float* __restrict__ bias, float* __restrict__ out3, int M)
{
  constexpr int LDT = 40;
  constexpr int K = 1664, NK = K / 32;
  __shared__ alignas(16) unsigned short Asm[2][128 * LDT];
  __shared__ alignas(16) unsigned short Bsm[2][128 * LDT];
  const int tid = threadIdx.x, lane = tid & 63;
  const int w = tid >> 6, wr = w >> 1, wc = w & 1;
  const int row0 = blockIdx.x * 128;
  const int srow = tid >> 2, slot = tid & 3;
  const int ar0 = min(row0 + srow, M - 1);
  const int ar1 = min(row0 + srow + 64, M - 1);
  const unsigned short* a0p = Xagg + (size_t)ar0 * 640;
  const unsigned short* a1p = Xagg + (size_t)ar1 * 640;
  const unsigned short* b0p = WT + (size_t)srow * K + slot * 8;
  const unsigned short* b1p = WT + (size_t)(srow + 64) * K + slot * 8;
  const float s10 = sc1[ar0], s20 = sc2[ar0];
  const float s11 = sc1[ar1], s21 = sc2[ar1];
  const int wa0 = srow * LDT + slot * 8, wa1 = wa0 + 64 * LDT;

  int offA[4], offB[4];
#pragma unroll
  for (int i = 0; i < 4; ++i) {
    offA[i] = (wr * 64 + i * 16 + (lane & 15)) * LDT + (lane >> 4) * 8;
    offB[i] = (wc * 64 + i * 16 + (lane & 15)) * LDT + (lane >> 4) * 8;
  }

  f32x4 acc[4][4] = {};
  uint4 a0 = loadA_fold(a0p, slot * 8, s10, s20);
  uint4 a1 = loadA_fold(a1p, slot * 8, s11, s21);
  uint4 b0 = *(const uint4*)b0p;
  uint4 b1 = *(const uint4*)b1p;
  *(uint4*)&Asm[0][wa0] = a0; *(uint4*)&Asm[0][wa1] = a1;
  *(uint4*)&Bsm[0][wa0] = b0; *(uint4*)&Bsm[0][wa1] = b1;
  __syncthreads();

  for (int kt = 0; kt < NK; ++kt) {
    const int cur = kt & 1;
    if (kt + 1 < NK) {
      const int kc = (kt + 1) * 32 + slot * 8;
      a0 = loadA_fold(a0p, kc, s10, s20);
      a1 = loadA_fold(a1p, kc, s11, s21);
      b0 = *(const uint4*)(b0p + (kt + 1) * 32);
      b1 = *(const uint4*)(b1p + (kt + 1) * 32);
    }
    s16x8 af[4], bq[4];
#pragma unroll
    for (int i = 0; i < 4; ++i) af[i] = *(const s16x8*)&Asm[cur][offA[i]];
#pragma unroll
    for (int i = 0; i < 4; ++i) bq[i] = *(const s16x8*)&Bsm[cur][offB[i]];
#pragma unroll
    for (int mi = 0; mi < 4; ++mi)
#pragma unroll
      for (int ni = 0; ni < 4; ++ni)
        acc[mi][ni] = __builtin_amdgcn_mfma_f32_16x16x32_bf16(af[mi], bq[ni], acc[mi][ni], 0, 0, 0);
    if (kt + 1 < NK) {
      const int nxt = cur ^ 1;
      *(uint4*)&Asm[nxt][wa0] = a0; *(uint4*)&Asm[nxt][wa1] = a1;
      *(uint4*)&Bsm[nxt][wa0] = b0; *(uint4*)&Bsm[nxt][wa1] = b1;
      __syncthreads();
    }
  }

#pragma unroll
  for (int mi = 0; mi < 4; ++mi) {
#pragma unroll
    for (int ni = 0; ni < 4; ++ni) {
      const int rbase = row0 + wr * 64 + mi * 16 + (lane >> 4) * 4;
      const int c = wc * 64 + ni * 16 + (lane & 15);
      const float badd = bias[c];
#pragma unroll
      for (int r = 0; r < 4; ++r) {
        const int rr = rbase + r;
        if (rr < M) out3[(size_t)rr * 128 + c] = acc[mi][ni][r] + badd;
      }
    }
  }
}

// ---------- BN stats ----------
__global__ void colreduce_kernel(const float* __restrict__ out3, float* __restrict__ bnsum, int n) {
  const int f = threadIdx.x;
  float s = 0.f, ss = 0.f;
  for (int r = blockIdx.x; r < n; r += gridDim.x) {
    const float v = out3[(size_t)r * 128 + f];
    s += v; ss += v * v;
  }
  atomicAdd(&bnsum[f], s);
  atomicAdd(&bnsum[128 + f], ss);
}

__global__ void bnfinal_kernel(const float* __restrict__ bnsum, const float* __restrict__ gamma,
                               const float* __restrict__ beta, float* __restrict__ sc,
                               float* __restrict__ shv, int n) {
  const int f = threadIdx.x;
  const float inv = 1.f / (float)n;
  const float mu = bnsum[f] * inv;
  const float var = bnsum[128 + f] * inv - mu * mu;
  const float rstd = rsqrtf(var + 1e-5f);
  const float s = gamma[f] * rstd;
  sc[f] = s;
  shv[f] = beta[f] - mu * s;
}

// ---------- BN apply + ReLU + residual ----------
__global__ void epilogue_kernel(const float* __restrict__ out3, const float* __restrict__ h,
                                const float* __restrict__ sc, const float* __restrict__ shv,
                                float* __restrict__ out, int total4) {
  int i = blockIdx.x * blockDim.x + threadIdx.x;
  if (i >= total4) return;
  const int c = (i & 31) * 4;
  const float4 x = ((const float4*)out3)[i];
  const float4 hh = ((const float4*)h)[i];
  float4 r;
  r.x = fmaxf(x.x * sc[c + 0] + shv[c + 0], 0.f) + hh.x;
  r.y = fmaxf(x.y * sc[c + 1] + shv[c + 1], 0.f) + hh.y;
  r.z = fmaxf(x.z * sc[c + 2] + shv[c + 2], 0.f) + hh.z;
  r.w = fmaxf(x.w * sc[c + 3] + shv[c + 3], 0.f) + hh.w;
  ((float4*)out)[i] = r;
}

extern "C" void kernel_launch(void* const* d_in, const int* in_sizes, int n_in,
                              void* d_out, int out_size, void* d_ws, size_t ws_size,
                              hipStream_t stream) {
  const float* h      = (const float*)d_in[0];
  const int*   ei     = (const int*)d_in[1];
  const float* W_pre  = (const float*)d_in[2];
  const float* b_pre  = (const float*)d_in[3];
  const float* W_post = (const float*)d_in[4];
  const float* b_post = (const float*)d_in[5];
  const float* W_lin  = (const float*)d_in[6];
  const float* b_lin  = (const float*)d_in[7];
  const float* gamma  = (const float*)d_in[8];
  const float* beta   = (const float*)d_in[9];

  const int n = in_sizes[0] / 128;
  const int E = in_sizes[1] / 2;
  const int* src = ei;
  const int* dst = ei + E;

  char* ws = (char*)d_ws;
  size_t off = 0;
  auto carve = [&](size_t bytes) {
    off = (off + 255) & ~(size_t)255;
    void* p = ws + off;
    off += bytes;
    return p;
  };
  unsigned short* hb   = (unsigned short*)carve((size_t)n * 128 * 2);
  void* ab_out3        = carve((size_t)n * 256 * 2);  // AB (bf16) then reused as out3 (f32), same bytes
  unsigned short* AB   = (unsigned short*)ab_out3;
  float* out3          = (float*)ab_out3;
  unsigned short* Xagg = (unsigned short*)carve((size_t)n * 640 * 2);
  float* sc1           = (float*)carve((size_t)n * 4);
  float* sc2           = (float*)carve((size_t)n * 4);
  unsigned short* WcatT  = (unsigned short*)carve(256 * 128 * 2);
  unsigned short* WfoldT = (unsigned short*)carve((size_t)128 * 1664 * 2);
  float* bfold         = (float*)carve(128 * 4);
  int*   cnt           = (int*)carve((size_t)n * 4);
  int*   rowptr        = (int*)carve((size_t)(n + 1) * 4);
  int*   cursor        = (int*)carve((size_t)n * 4);
  int*   ssrc          = (int*)carve((size_t)E * 4);
  float* bnsum         = (float*)carve(256 * 4);
  float* bnsc          = (float*)carve(128 * 4);
  float* bnsh          = (float*)carve(128 * 4);

  const int total4 = n * 128 / 4;
  const int mt = (n + 127) / 128;

  conv_h_kernel<<<(total4 + 255) / 256, 256, 0, stream>>>(h, hb, total4);
  fold_wcat_kernel<<<128, 256, 0, stream>>>(W_pre, WcatT);
  fold_wpost_kernel<<<1665, 128, 0, stream>>>(W_post, b_post, W_lin, b_lin, WfoldT, bfold);

  hipMemsetAsync(cnt, 0, (size_t)n * 4, stream);
  hist_kernel<<<(E + 255) / 256, 256, 0, stream>>>(dst, cnt, E);
  scan_kernel<<<1, 1024, 0, stream>>>(cnt, rowptr, cursor, n);
  scatter_kernel<<<(E + 255) / 256, 256, 0, stream>>>(src, dst, cursor, ssrc, E);

  gemm256_kernel<<<dim3(mt, 2), 256, 0, stream>>>(hb, WcatT, AB, n);
  aggregate_kernel<<<(n + 3) / 4, 256, 0, stream>>>(AB, hb, b_pre, rowptr, ssrc, Xagg, sc1, sc2, n);
  gemm_fold_kernel<<<dim3(mt, 1), 256, 0, stream>>>(Xagg, sc1, sc2, WfoldT, bfold, out3, n);

  hipMemsetAsync(bnsum, 0, 256 * 4, stream);
  colreduce_kernel<<<512, 128, 0, stream>>>(out3, bnsum, n);
  bnfinal_kernel<<<1, 128, 0, stream>>>(bnsum, gamma, beta, bnsc, bnsh, n);
  epilogue_kernel<<<(total4 + 255) / 256, 256, 0, stream>>>(out3, h, bnsc, bnsh, (float*)d_out, total4);
}

// Round 3
// 379.454 us; speedup vs baseline: 1.2917x; 1.2917x over previous
//
#include <hip/hip_runtime.h>
#include <hip/hip_bf16.h>
#include <cstdint>
#include <cstddef>

typedef short s16x8 __attribute__((ext_vector_type(8)));
typedef float f32x4 __attribute__((ext_vector_type(4)));

#define AVG_LOG_F 2.8332133f  // ln(17)

static __device__ __forceinline__ float b2f(unsigned short u) {
  union { unsigned int i; float f; } x; x.i = ((unsigned int)u) << 16; return x.f;
}
static __device__ __forceinline__ unsigned short f2b(float f) {
  __hip_bfloat16 h = __float2bfloat16(f);
  union { __hip_bfloat16 hh; unsigned short u; } c; c.hh = h; return c.u;
}
static __device__ __forceinline__ unsigned int pack2(float lo, float hi) {
  return (unsigned int)f2b(lo) | ((unsigned int)f2b(hi) << 16);
}

// ---------- h fp32 -> bf16 (4 floats / thread) ----------
__global__ void conv_h_kernel(const float* __restrict__ h, unsigned short* __restrict__ hb, int total4) {
  int i = blockIdx.x * blockDim.x + threadIdx.x;
  if (i >= total4) return;
  const float4 v = ((const float4*)h)[i];
  uint2 r;
  r.x = pack2(v.x, v.y);
  r.y = pack2(v.z, v.w);
  ((uint2*)hb)[i] = r;
}

// ---------- WcatT[c][k]: c<128 -> W_pre[k][c] (dst half), else W_pre[128+k][c-128] (src half) ----------
__global__ void fold_wcat_kernel(const float* __restrict__ W_pre, unsigned short* __restrict__ WcatT) {
  int idx = blockIdx.x * blockDim.x + threadIdx.x;  // 256*128 total
  int c = idx >> 7, k = idx & 127;
  float v = (c < 128) ? W_pre[k * 128 + c] : W_pre[(128 + k) * 128 + (c - 128)];
  WcatT[c * 128 + k] = f2b(v);
}

// ---------- WfoldT[j][i] = sum_k W_post[i][k]*W_lin[k][j]; block 1664 computes bfold ----------
__global__ void fold_wpost_kernel(const float* __restrict__ W_post, const float* __restrict__ b_post,
                                  const float* __restrict__ W_lin, const float* __restrict__ b_lin,
                                  unsigned short* __restrict__ WfoldT, float* __restrict__ bfold) {
  const int j = threadIdx.x;
  const int i = blockIdx.x;
  if (i == 1664) {
    float acc = b_lin[j];
    for (int k = 0; k < 128; ++k) acc += b_post[k] * W_lin[k * 128 + j];
    bfold[j] = acc;
  } else {
    float acc = 0.f;
    for (int k = 0; k < 128; ++k) acc += W_post[i * 128 + k] * W_lin[k * 128 + j];
    WfoldT[(size_t)j * 1664 + i] = f2b(acc);
  }
}

// ---------- CSR build ----------
__global__ void hist_kernel(const int* __restrict__ dst, int* __restrict__ cnt, int E) {
  const int e = blockIdx.x * blockDim.x + threadIdx.x;
  if (e < E) atomicAdd(&cnt[dst[e]], 1);
}

// 3-phase parallel scan (order within CSR groups is irrelevant; only offsets must be exact)
__global__ void scan1_kernel(const int* __restrict__ cnt, int* __restrict__ bsum, int n) {
  __shared__ int sh[256];
  const int tid = threadIdx.x;
  const int i = blockIdx.x * 256 + tid;
  sh[tid] = (i < n) ? cnt[i] : 0;
  __syncthreads();
  for (int o = 128; o > 0; o >>= 1) {
    if (tid < o) sh[tid] += sh[tid + o];
    __syncthreads();
  }
  if (tid == 0) bsum[blockIdx.x] = sh[0];
}

__global__ void scan2_kernel(int* __restrict__ bsum, int* __restrict__ rowptr, int n, int nb) {
  __shared__ int sh[256];
  const int tid = threadIdx.x;
  const int CH = (nb + 255) / 256;
  const int lo = tid * CH, hi = min(lo + CH, nb);
  int sum = 0;
  for (int i = lo; i < hi; ++i) sum += bsum[i];
  sh[tid] = sum;
  __syncthreads();
  for (int o = 1; o < 256; o <<= 1) {
    int t = (tid >= o) ? sh[tid - o] : 0;
    __syncthreads();
    sh[tid] += t;
    __syncthreads();
  }
  int run = sh[tid] - sum;  // exclusive prefix of this chunk
  for (int i = lo; i < hi; ++i) {
    int v = bsum[i];
    bsum[i] = run;
    run += v;
  }
  if (tid == 255) rowptr[n] = sh[255];
}

__global__ void scan3_kernel(const int* __restrict__ cnt, const int* __restrict__ bsum,
                             int* __restrict__ rowptr, int* __restrict__ cursor, int n) {
  __shared__ int sh[256];
  const int tid = threadIdx.x;
  const int i = blockIdx.x * 256 + tid;
  const int v = (i < n) ? cnt[i] : 0;
  sh[tid] = v;
  __syncthreads();
  for (int o = 1; o < 256; o <<= 1) {
    int t = (tid >= o) ? sh[tid - o] : 0;
    __syncthreads();
    sh[tid] += t;
    __syncthreads();
  }
  if (i < n) {
    const int p = bsum[blockIdx.x] + sh[tid] - v;  // global exclusive prefix
    rowptr[i] = p;
    cursor[i] = p;
  }
}

__global__ void scatter_kernel(const int* __restrict__ src, const int* __restrict__ dst,
                               int* __restrict__ cursor, int* __restrict__ ssrc, int E) {
  const int e = blockIdx.x * blockDim.x + threadIdx.x;
  if (e < E) {
    const int d = dst[e];
    const int p = atomicAdd(&cursor[d], 1);
    ssrc[p] = src[e];
  }
}

// ---------- GEMM 1: AB[M,256] = hb[M,128] @ WcatT[256,128]^T, bf16 out ----------
__global__ __launch_bounds__(256) void gemm256_kernel(
    const unsigned short* __restrict__ A, const unsigned short* __restrict__ BT,
    unsigned short* __restrict__ outb, int M)
{
  constexpr int LDT = 40;  // 32 + 8 pad: max 2-way LDS aliasing (free per m136)
  constexpr int K = 128, NK = K / 32;
  __shared__ alignas(16) unsigned short Asm[2][128 * LDT];
  __shared__ alignas(16) unsigned short Bsm[2][128 * LDT];
  const int tid = threadIdx.x, lane = tid & 63;
  const int w = tid >> 6, wr = w >> 1, wc = w & 1;
  const int row0 = blockIdx.x * 128;
  const int col0 = blockIdx.y * 128;
  const int srow = tid >> 2, slot = tid & 3;
  const int ar0 = min(row0 + srow, M - 1);
  const int ar1 = min(row0 + srow + 64, M - 1);
  const unsigned short* ap0 = A + (size_t)ar0 * K + slot * 8;
  const unsigned short* ap1 = A + (size_t)ar1 * K + slot * 8;
  const unsigned short* bp0 = BT + (size_t)(col0 + srow) * K + slot * 8;
  const unsigned short* bp1 = BT + (size_t)(col0 + srow + 64) * K + slot * 8;
  const int wa0 = srow * LDT + slot * 8, wa1 = wa0 + 64 * LDT;

  int offA[4], offB[4];
#pragma unroll
  for (int i = 0; i < 4; ++i) {
    offA[i] = (wr * 64 + i * 16 + (lane & 15)) * LDT + (lane >> 4) * 8;
    offB[i] = (wc * 64 + i * 16 + (lane & 15)) * LDT + (lane >> 4) * 8;
  }

  f32x4 acc[4][4] = {};
  uint4 a0 = *(const uint4*)ap0;
  uint4 a1 = *(const uint4*)ap1;
  uint4 b0 = *(const uint4*)bp0;
  uint4 b1 = *(const uint4*)bp1;
  *(uint4*)&Asm[0][wa0] = a0; *(uint4*)&Asm[0][wa1] = a1;
  *(uint4*)&Bsm[0][wa0] = b0; *(uint4*)&Bsm[0][wa1] = b1;
  __syncthreads();

  for (int kt = 0; kt < NK; ++kt) {
    const int cur = kt & 1;
    if (kt + 1 < NK) {
      const int k0 = (kt + 1) * 32;
      a0 = *(const uint4*)(ap0 + k0); a1 = *(const uint4*)(ap1 + k0);
      b0 = *(const uint4*)(bp0 + k0); b1 = *(const uint4*)(bp1 + k0);
    }
    s16x8 af[4], bq[4];
#pragma unroll
    for (int i = 0; i < 4; ++i) af[i] = *(const s16x8*)&Asm[cur][offA[i]];
#pragma unroll
    for (int i = 0; i < 4; ++i) bq[i] = *(const s16x8*)&Bsm[cur][offB[i]];
#pragma unroll
    for (int mi = 0; mi < 4; ++mi)
#pragma unroll
      for (int ni = 0; ni < 4; ++ni)
        acc[mi][ni] = __builtin_amdgcn_mfma_f32_16x16x32_bf16(af[mi], bq[ni], acc[mi][ni], 0, 0, 0);
    if (kt + 1 < NK) {
      const int nxt = cur ^ 1;
      *(uint4*)&Asm[nxt][wa0] = a0; *(uint4*)&Asm[nxt][wa1] = a1;
      *(uint4*)&Bsm[nxt][wa0] = b0; *(uint4*)&Bsm[nxt][wa1] = b1;
      __syncthreads();
    }
  }

#pragma unroll
  for (int mi = 0; mi < 4; ++mi) {
#pragma unroll
    for (int ni = 0; ni < 4; ++ni) {
      const int rbase = row0 + wr * 64 + mi * 16 + (lane >> 4) * 4;
      const int c = col0 + wc * 64 + ni * 16 + (lane & 15);
#pragma unroll
      for (int r = 0; r < 4; ++r) {
        const int rr = rbase + r;
        if (rr < M) outb[(size_t)rr * 256 + c] = f2b(acc[mi][ni][r]);
      }
    }
  }
}

// ---------- per-node aggregation: one wave per node, 2 feature cols per lane ----------
__global__ void aggregate_kernel(const unsigned short* __restrict__ AB,
                                 const unsigned short* __restrict__ hb,
                                 const float* __restrict__ b_pre,
                                 const int* __restrict__ rowptr, const int* __restrict__ ssrc,
                                 unsigned short* __restrict__ Xagg,
                                 float* __restrict__ sc1, float* __restrict__ sc2, int n) {
  const int node = blockIdx.x * 4 + (threadIdx.x >> 6);
  if (node >= n) return;
  const int lane = threadIdx.x & 63;
  const int beg = rowptr[node], end = rowptr[node + 1];
  const int cnt = end - beg;
  float s0 = 0.f, s1v = 0.f, q0 = 0.f, q1 = 0.f;
  float mn0 = 3.4e38f, mn1 = 3.4e38f, mx0 = -3.4e38f, mx1 = -3.4e38f;
  for (int base = beg; base < end; base += 64) {
    const int mcnt = min(64, end - base);
    const int myidx = (base + lane < end) ? ssrc[base + lane] : 0;
#pragma unroll 4
    for (int t = 0; t < mcnt; ++t) {
      const int sidx = __shfl(myidx, t);
      const unsigned int v = *(const unsigned int*)(AB + (size_t)sidx * 256 + 128 + 2 * lane);
      const float v0 = b2f((unsigned short)(v & 0xffffu));
      const float v1 = b2f((unsigned short)(v >> 16));
      s0 += v0; q0 += v0 * v0; mn0 = fminf(mn0, v0); mx0 = fmaxf(mx0, v0);
      s1v += v1; q1 += v1 * v1; mn1 = fminf(mn1, v1); mx1 = fmaxf(mx1, v1);
    }
  }
  const float degf = (float)(cnt > 0 ? cnt : 1);
  const float2 bp = ((const float2*)b_pre)[lane];
  const unsigned int cpair = *(const unsigned int*)(AB + (size_t)node * 256 + 2 * lane);
  const float c0 = b2f((unsigned short)(cpair & 0xffffu)) + bp.x;
  const float c1 = b2f((unsigned short)(cpair >> 16)) + bp.y;
  float mean0, mean1, std0, std1, lo0, lo1, hi0, hi1;
  if (cnt > 0) {
    const float inv = 1.f / degf;
    const float mu0 = s0 * inv, mu1 = s1v * inv;
    mean0 = c0 + mu0; mean1 = c1 + mu1;
    std0 = sqrtf(fmaxf(q0 * inv - mu0 * mu0, 0.f) + 1e-5f);
    std1 = sqrtf(fmaxf(q1 * inv - mu1 * mu1, 0.f) + 1e-5f);
    lo0 = c0 + mn0; lo1 = c1 + mn1; hi0 = c0 + mx0; hi1 = c1 + mx1;
  } else {
    mean0 = mean1 = lo0 = lo1 = hi0 = hi1 = 0.f;
    std0 = std1 = sqrtf(1e-5f);
  }
  const float logd = logf(degf + 1.f);
  unsigned int* row = (unsigned int*)(Xagg + (size_t)node * 640);
  row[lane]       = *(const unsigned int*)(hb + (size_t)node * 128 + 2 * lane);
  row[64 + lane]  = pack2(mean0, mean1);
  row[128 + lane] = pack2(lo0, lo1);
  row[192 + lane] = pack2(hi0, hi1);
  row[256 + lane] = pack2(std0, std1);
  if (lane == 0) { sc1[node] = logd / AVG_LOG_F; sc2[node] = AVG_LOG_F / logd; }
}

// ---------- GEMM 2: out3[M,128] = X13[M,1664] @ WfoldT[128,1664]^T + bfold, ----------
// ---------- X13 synthesized at staging: k<640 -> Xagg[k]; k<1152 -> Xagg[k-512]*s1; else Xagg[k-1024]*s2 ----------
static __device__ __forceinline__ uint4 scale8(uint4 r, float s) {
  union { uint4 v; unsigned short h[8]; } in, out;
  in.v = r;
#pragma unroll
  for (int i = 0; i < 8; ++i) out.h[i] = f2b(b2f(in.h[i]) * s);
  return out.v;
}
static __device__ __forceinline__ uint4 loadA_fold(const unsigned short* base, int kc,
                                                   float s1v, float s2v) {
  const bool m1 = kc >= 640;
  const bool m2 = kc >= 1152;
  const int off = kc - (m1 ? 512 : 0) - (m2 ? 512 : 0);
  uint4 r = *(const uint4*)(base + off);
  if (m1) r = scale8(r, m2 ? s2v : s1v);
  return r;
}

__global__ __launch_bounds__(256) void gemm_fold_kernel(
    const unsigned short* __restrict__ Xagg, const float* __restrict__ sc1,
    const float* __restrict__ sc2, const unsigned short* __restrict__ WT,
    const float* __restrict__ bias, float* __restrict__ out3, int M)
{
  constexpr int LDT = 40;
  constexpr int K = 1664, NK = K / 32;
  __shared__ alignas(16) unsigned short Asm[2][128 * LDT];
  __shared__ alignas(16) unsigned short Bsm[2][128 * LDT];
  const int tid = threadIdx.x, lane = tid & 63;
  const int w = tid >> 6, wr = w >> 1, wc = w & 1;
  const int row0 = blockIdx.x * 128;
  const int srow = tid >> 2, slot = tid & 3;
  const int ar0 = min(row0 + srow, M - 1);
  const int ar1 = min(row0 + srow + 64, M - 1);
  const unsigned short* a0p = Xagg + (size_t)ar0 * 640;
  const unsigned short* a1p = Xagg + (size_t)ar1 * 640;
  const unsigned short* b0p = WT + (size_t)srow * K + slot * 8;
  const unsigned short* b1p = WT + (size_t)(srow + 64) * K + slot * 8;
  const float s10 = sc1[ar0], s20 = sc2[ar0];
  const float s11 = sc1[ar1], s21 = sc2[ar1];
  const int wa0 = srow * LDT + slot * 8, wa1 = wa0 + 64 * LDT;

  int offA[4], offB[4];
#pragma unroll
  for (int i = 0; i < 4; ++i) {
    offA[i] = (wr * 64 + i * 16 + (lane & 15)) * LDT + (lane >> 4) * 8;
    offB[i] = (wc * 64 + i * 16 + (lane & 15)) * LDT + (lane >> 4) * 8;
  }

  f32x4 acc[4][4] = {};
  uint4 a0 = loadA_fold(a0p, slot * 8, s10, s20);
  uint4 a1 = loadA_fold(a1p, slot * 8, s11, s21);
  uint4 b0 = *(const uint4*)b0p;
  uint4 b1 = *(const uint4*)b1p;
  *(uint4*)&Asm[0][wa0] = a0; *(uint4*)&Asm[0][wa1] = a1;
  *(uint4*)&Bsm[0][wa0] = b0; *(uint4*)&Bsm[0][wa1] = b1;
  __syncthreads();

  for (int kt = 0; kt < NK; ++kt) {
    const int cur = kt & 1;
    if (kt + 1 < NK) {
      const int kc = (kt + 1) * 32 + slot * 8;
      a0 = loadA_fold(a0p, kc, s10, s20);
      a1 = loadA_fold(a1p, kc, s11, s21);
      b0 = *(const uint4*)(b0p + (kt + 1) * 32);
      b1 = *(const uint4*)(b1p + (kt + 1) * 32);
    }
    s16x8 af[4], bq[4];
#pragma unroll
    for (int i = 0; i < 4; ++i) af[i] = *(const s16x8*)&Asm[cur][offA[i]];
#pragma unroll
    for (int i = 0; i < 4; ++i) bq[i] = *(const s16x8*)&Bsm[cur][offB[i]];
#pragma unroll
    for (int mi = 0; mi < 4; ++mi)
#pragma unroll
      for (int ni = 0; ni < 4; ++ni)
        acc[mi][ni] = __builtin_amdgcn_mfma_f32_16x16x32_bf16(af[mi], bq[ni], acc[mi][ni], 0, 0, 0);
    if (kt + 1 < NK) {
      const int nxt = cur ^ 1;
      *(uint4*)&Asm[nxt][wa0] = a0; *(uint4*)&Asm[nxt][wa1] = a1;
      *(uint4*)&Bsm[nxt][wa0] = b0; *(uint4*)&Bsm[nxt][wa1] = b1;
      __syncthreads();
    }
  }

#pragma unroll
  for (int mi = 0; mi < 4; ++mi) {
#pragma unroll
    for (int ni = 0; ni < 4; ++ni) {
      const int rbase = row0 + wr * 64 + mi * 16 + (lane >> 4) * 4;
      const int c = wc * 64 + ni * 16 + (lane & 15);
      const float badd = bias[c];
#pragma unroll
      for (int r = 0; r < 4; ++r) {
        const int rr = rbase + r;
        if (rr < M) out3[(size_t)rr * 128 + c] = acc[mi][ni][r] + badd;
      }
    }
  }
}

// ---------- BN stats ----------
__global__ void colreduce_kernel(const float* __restrict__ out3, float* __restrict__ bnsum, int n) {
  const int f = threadIdx.x;
  float s = 0.f, ss = 0.f;
  for (int r = blockIdx.x; r < n; r += gridDim.x) {
    const float v = out3[(size_t)r * 128 + f];
    s += v; ss += v * v;
  }
  atomicAdd(&bnsum[f], s);
  atomicAdd(&bnsum[128 + f], ss);
}

__global__ void bnfinal_kernel(const float* __restrict__ bnsum, const float* __restrict__ gamma,
                               const float* __restrict__ beta, float* __restrict__ sc,
                               float* __restrict__ shv, int n) {
  const int f = threadIdx.x;
  const float inv = 1.f / (float)n;
  const float mu = bnsum[f] * inv;
  const float var = bnsum[128 + f] * inv - mu * mu;
  const float rstd = rsqrtf(var + 1e-5f);
  const float s = gamma[f] * rstd;
  sc[f] = s;
  shv[f] = beta[f] - mu * s;
}

// ---------- BN apply + ReLU + residual ----------
__global__ void epilogue_kernel(const float* __restrict__ out3, const float* __restrict__ h,
                                const float* __restrict__ sc, const float* __restrict__ shv,
                                float* __restrict__ out, int total4) {
  int i = blockIdx.x * blockDim.x + threadIdx.x;
  if (i >= total4) return;
  const int c = (i & 31) * 4;
  const float4 x = ((const float4*)out3)[i];
  const float4 hh = ((const float4*)h)[i];
  float4 r;
  r.x = fmaxf(x.x * sc[c + 0] + shv[c + 0], 0.f) + hh.x;
  r.y = fmaxf(x.y * sc[c + 1] + shv[c + 1], 0.f) + hh.y;
  r.z = fmaxf(x.z * sc[c + 2] + shv[c + 2], 0.f) + hh.z;
  r.w = fmaxf(x.w * sc[c + 3] + shv[c + 3], 0.f) + hh.w;
  ((float4*)out)[i] = r;
}

extern "C" void kernel_launch(void* const* d_in, const int* in_sizes, int n_in,
                              void* d_out, int out_size, void* d_ws, size_t ws_size,
                              hipStream_t stream) {
  const float* h      = (const float*)d_in[0];
  const int*   ei     = (const int*)d_in[1];
  const float* W_pre  = (const float*)d_in[2];
  const float* b_pre  = (const float*)d_in[3];
  const float* W_post = (const float*)d_in[4];
  const float* b_post = (const float*)d_in[5];
  const float* W_lin  = (const float*)d_in[6];
  const float* b_lin  = (const float*)d_in[7];
  const float* gamma  = (const float*)d_in[8];
  const float* beta   = (const float*)d_in[9];

  const int n = in_sizes[0] / 128;
  const int E = in_sizes[1] / 2;
  const int* src = ei;
  const int* dst = ei + E;

  char* ws = (char*)d_ws;
  size_t off = 0;
  auto carve = [&](size_t bytes) {
    off = (off + 255) & ~(size_t)255;
    void* p = ws + off;
    off += bytes;
    return p;
  };
  unsigned short* hb   = (unsigned short*)carve((size_t)n * 128 * 2);
  void* ab_out3        = carve((size_t)n * 256 * 2);  // AB (bf16) then reused as out3 (f32), same bytes
  unsigned short* AB   = (unsigned short*)ab_out3;
  float* out3          = (float*)ab_out3;
  unsigned short* Xagg = (unsigned short*)carve((size_t)n * 640 * 2);
  float* sc1           = (float*)carve((size_t)n * 4);
  float* sc2           = (float*)carve((size_t)n * 4);
  unsigned short* WcatT  = (unsigned short*)carve(256 * 128 * 2);
  unsigned short* WfoldT = (unsigned short*)carve((size_t)128 * 1664 * 2);
  float* bfold         = (float*)carve(128 * 4);
  int*   cnt           = (int*)carve((size_t)n * 4);
  int*   rowptr        = (int*)carve((size_t)(n + 1) * 4);
  int*   cursor        = (int*)carve((size_t)n * 4);
  int*   ssrc          = (int*)carve((size_t)E * 4);
  int*   bsum          = (int*)carve((size_t)256 * 4);
  float* bnsum         = (float*)carve(256 * 4);
  float* bnsc          = (float*)carve(128 * 4);
  float* bnsh          = (float*)carve(128 * 4);

  const int total4 = n * 128 / 4;
  const int mt = (n + 127) / 128;
  const int nb = (n + 255) / 256;  // scan blocks (196 for n=50000; scan2 handles nb<=65536)

  conv_h_kernel<<<(total4 + 255) / 256, 256, 0, stream>>>(h, hb, total4);
  fold_wcat_kernel<<<128, 256, 0, stream>>>(W_pre, WcatT);
  fold_wpost_kernel<<<1665, 128, 0, stream>>>(W_post, b_post, W_lin, b_lin, WfoldT, bfold);

  hipMemsetAsync(cnt, 0, (size_t)n * 4, stream);
  hist_kernel<<<(E + 255) / 256, 256, 0, stream>>>(dst, cnt, E);
  scan1_kernel<<<nb, 256, 0, stream>>>(cnt, bsum, n);
  scan2_kernel<<<1, 256, 0, stream>>>(bsum, rowptr, n, nb);
  scan3_kernel<<<nb, 256, 0, stream>>>(cnt, bsum, rowptr, cursor, n);
  scatter_kernel<<<(E + 255) / 256, 256, 0, stream>>>(src, dst, cursor, ssrc, E);

  gemm256_kernel<<<dim3(mt, 2), 256, 0, stream>>>(hb, WcatT, AB, n);
  aggregate_kernel<<<(n + 3) / 4, 256, 0, stream>>>(AB, hb, b_pre, rowptr, ssrc, Xagg, sc1, sc2, n);
  gemm_fold_kernel<<<dim3(mt, 1), 256, 0, stream>>>(Xagg, sc1, sc2, WfoldT, bfold, out3, n);

  hipMemsetAsync(bnsum, 0, 256 * 4, stream);
  colreduce_kernel<<<512, 128, 0, stream>>>(out3, bnsum, n);
  bnfinal_kernel<<<1, 128, 0, stream>>>(bnsum, gamma, beta, bnsc, bnsh, n);
  epilogue_kernel<<<(total4 + 255) / 256, 256, 0, stream>>>(out3, h, bnsc, bnsh, (float*)d_out, total4);
}

// Round 4
// 366.139 us; speedup vs baseline: 1.3386x; 1.0364x over previous
//
#include <hip/hip_runtime.h>
#include <hip/hip_bf16.h>
#include <cstdint>
#include <cstddef>

typedef short s16x8 __attribute__((ext_vector_type(8)));
typedef float f32x4 __attribute__((ext_vector_type(4)));

#define AVG_LOG_F 2.8332133f  // ln(17)

static __device__ __forceinline__ float b2f(unsigned short u) {
  union { unsigned int i; float f; } x; x.i = ((unsigned int)u) << 16; return x.f;
}
static __device__ __forceinline__ unsigned short f2b(float f) {
  __hip_bfloat16 h = __float2bfloat16(f);
  union { __hip_bfloat16 hh; unsigned short u; } c; c.hh = h; return c.u;
}
static __device__ __forceinline__ unsigned int pack2(float lo, float hi) {
  return (unsigned int)f2b(lo) | ((unsigned int)f2b(hi) << 16);
}

// ---------- h fp32 -> bf16 (4 floats / thread) ----------
__global__ void conv_h_kernel(const float* __restrict__ h, unsigned short* __restrict__ hb, int total4) {
  int i = blockIdx.x * blockDim.x + threadIdx.x;
  if (i >= total4) return;
  const float4 v = ((const float4*)h)[i];
  uint2 r;
  r.x = pack2(v.x, v.y);
  r.y = pack2(v.z, v.w);
  ((uint2*)hb)[i] = r;
}

// ---------- WcatT[c][k]: c<128 -> W_pre[k][c] (dst half), else W_pre[128+k][c-128] (src half) ----------
__global__ void fold_wcat_kernel(const float* __restrict__ W_pre, unsigned short* __restrict__ WcatT) {
  int idx = blockIdx.x * blockDim.x + threadIdx.x;  // 256*128 total
  int c = idx >> 7, k = idx & 127;
  float v = (c < 128) ? W_pre[k * 128 + c] : W_pre[(128 + k) * 128 + (c - 128)];
  WcatT[c * 128 + k] = f2b(v);
}

// ---------- WfoldT[j][i] = sum_k W_post[i][k]*W_lin[k][j]; block 208 computes bfold ----------
// W_lin staged in LDS once per block; 8 output rows per block.
__global__ __launch_bounds__(128) void fold_wpost_kernel(
    const float* __restrict__ W_post, const float* __restrict__ b_post,
    const float* __restrict__ W_lin, const float* __restrict__ b_lin,
    unsigned short* __restrict__ WfoldT, float* __restrict__ bfold) {
  __shared__ float wl[128 * 128];
  const int j = threadIdx.x;
  for (int r = 0; r < 128; ++r) wl[r * 128 + j] = W_lin[r * 128 + j];
  __syncthreads();
  if (blockIdx.x == 208) {
    float acc = b_lin[j];
    for (int k = 0; k < 128; ++k) acc += b_post[k] * wl[k * 128 + j];
    bfold[j] = acc;
  } else {
#pragma unroll 2
    for (int ii = 0; ii < 8; ++ii) {
      const int i = blockIdx.x * 8 + ii;
      float acc = 0.f;
      for (int k = 0; k < 128; ++k) acc += W_post[i * 128 + k] * wl[k * 128 + j];
      WfoldT[(size_t)j * 1664 + i] = f2b(acc);
    }
  }
}

// ---------- CSR build ----------
__global__ void hist_kernel(const int* __restrict__ dst, int* __restrict__ cnt, int E) {
  const int e = blockIdx.x * blockDim.x + threadIdx.x;
  if (e < E) atomicAdd(&cnt[dst[e]], 1);
}

// 3-phase parallel scan
__global__ void scan1_kernel(const int* __restrict__ cnt, int* __restrict__ bsum, int n) {
  __shared__ int sh[256];
  const int tid = threadIdx.x;
  const int i = blockIdx.x * 256 + tid;
  sh[tid] = (i < n) ? cnt[i] : 0;
  __syncthreads();
  for (int o = 128; o > 0; o >>= 1) {
    if (tid < o) sh[tid] += sh[tid + o];
    __syncthreads();
  }
  if (tid == 0) bsum[blockIdx.x] = sh[0];
}

__global__ void scan2_kernel(int* __restrict__ bsum, int* __restrict__ rowptr, int n, int nb) {
  __shared__ int sh[256];
  const int tid = threadIdx.x;
  const int CH = (nb + 255) / 256;
  const int lo = tid * CH, hi = min(lo + CH, nb);
  int sum = 0;
  for (int i = lo; i < hi; ++i) sum += bsum[i];
  sh[tid] = sum;
  __syncthreads();
  for (int o = 1; o < 256; o <<= 1) {
    int t = (tid >= o) ? sh[tid - o] : 0;
    __syncthreads();
    sh[tid] += t;
    __syncthreads();
  }
  int run = sh[tid] - sum;
  for (int i = lo; i < hi; ++i) {
    int v = bsum[i];
    bsum[i] = run;
    run += v;
  }
  if (tid == 255) rowptr[n] = sh[255];
}

__global__ void scan3_kernel(const int* __restrict__ cnt, const int* __restrict__ bsum,
                             int* __restrict__ rowptr, int* __restrict__ cursor, int n) {
  __shared__ int sh[256];
  const int tid = threadIdx.x;
  const int i = blockIdx.x * 256 + tid;
  const int v = (i < n) ? cnt[i] : 0;
  sh[tid] = v;
  __syncthreads();
  for (int o = 1; o < 256; o <<= 1) {
    int t = (tid >= o) ? sh[tid - o] : 0;
    __syncthreads();
    sh[tid] += t;
    __syncthreads();
  }
  if (i < n) {
    const int p = bsum[blockIdx.x] + sh[tid] - v;
    rowptr[i] = p;
    cursor[i] = p;
  }
}

__global__ void scatter_kernel(const int* __restrict__ src, const int* __restrict__ dst,
                               int* __restrict__ cursor, int* __restrict__ ssrc, int E) {
  const int e = blockIdx.x * blockDim.x + threadIdx.x;
  if (e < E) {
    const int d = dst[e];
    const int p = atomicAdd(&cursor[d], 1);
    ssrc[p] = src[e];
  }
}

// ---------- GEMM 1: AB[M,256] = hb[M,128] @ WcatT[256,128]^T, bf16 out ----------
__global__ __launch_bounds__(256) void gemm256_kernel(
    const unsigned short* __restrict__ A, const unsigned short* __restrict__ BT,
    unsigned short* __restrict__ outb, int M)
{
  constexpr int LDT = 40;
  constexpr int K = 128, NK = K / 32;
  __shared__ alignas(16) unsigned short Asm[2][128 * LDT];
  __shared__ alignas(16) unsigned short Bsm[2][128 * LDT];
  const int tid = threadIdx.x, lane = tid & 63;
  const int w = tid >> 6, wr = w >> 1, wc = w & 1;
  const int row0 = blockIdx.x * 128;
  const int col0 = blockIdx.y * 128;
  const int srow = tid >> 2, slot = tid & 3;
  const int ar0 = min(row0 + srow, M - 1);
  const int ar1 = min(row0 + srow + 64, M - 1);
  const unsigned short* ap0 = A + (size_t)ar0 * K + slot * 8;
  const unsigned short* ap1 = A + (size_t)ar1 * K + slot * 8;
  const unsigned short* bp0 = BT + (size_t)(col0 + srow) * K + slot * 8;
  const unsigned short* bp1 = BT + (size_t)(col0 + srow + 64) * K + slot * 8;
  const int wa0 = srow * LDT + slot * 8, wa1 = wa0 + 64 * LDT;

  int offA[4], offB[4];
#pragma unroll
  for (int i = 0; i < 4; ++i) {
    offA[i] = (wr * 64 + i * 16 + (lane & 15)) * LDT + (lane >> 4) * 8;
    offB[i] = (wc * 64 + i * 16 + (lane & 15)) * LDT + (lane >> 4) * 8;
  }

  f32x4 acc[4][4] = {};
  uint4 a0 = *(const uint4*)ap0;
  uint4 a1 = *(const uint4*)ap1;
  uint4 b0 = *(const uint4*)bp0;
  uint4 b1 = *(const uint4*)bp1;
  *(uint4*)&Asm[0][wa0] = a0; *(uint4*)&Asm[0][wa1] = a1;
  *(uint4*)&Bsm[0][wa0] = b0; *(uint4*)&Bsm[0][wa1] = b1;
  __syncthreads();

  for (int kt = 0; kt < NK; ++kt) {
    const int cur = kt & 1;
    if (kt + 1 < NK) {
      const int k0 = (kt + 1) * 32;
      a0 = *(const uint4*)(ap0 + k0); a1 = *(const uint4*)(ap1 + k0);
      b0 = *(const uint4*)(bp0 + k0); b1 = *(const uint4*)(bp1 + k0);
    }
    s16x8 af[4], bq[4];
#pragma unroll
    for (int i = 0; i < 4; ++i) af[i] = *(const s16x8*)&Asm[cur][offA[i]];
#pragma unroll
    for (int i = 0; i < 4; ++i) bq[i] = *(const s16x8*)&Bsm[cur][offB[i]];
#pragma unroll
    for (int mi = 0; mi < 4; ++mi)
#pragma unroll
      for (int ni = 0; ni < 4; ++ni)
        acc[mi][ni] = __builtin_amdgcn_mfma_f32_16x16x32_bf16(af[mi], bq[ni], acc[mi][ni], 0, 0, 0);
    if (kt + 1 < NK) {
      const int nxt = cur ^ 1;
      *(uint4*)&Asm[nxt][wa0] = a0; *(uint4*)&Asm[nxt][wa1] = a1;
      *(uint4*)&Bsm[nxt][wa0] = b0; *(uint4*)&Bsm[nxt][wa1] = b1;
      __syncthreads();
    }
  }

#pragma unroll
  for (int mi = 0; mi < 4; ++mi) {
#pragma unroll
    for (int ni = 0; ni < 4; ++ni) {
      const int rbase = row0 + wr * 64 + mi * 16 + (lane >> 4) * 4;
      const int c = col0 + wc * 64 + ni * 16 + (lane & 15);
#pragma unroll
      for (int r = 0; r < 4; ++r) {
        const int rr = rbase + r;
        if (rr < M) outb[(size_t)rr * 256 + c] = f2b(acc[mi][ni][r]);
      }
    }
  }
}

// ---------- per-node aggregation: one wave per node; readlane-indexed saddr gathers ----------
#define AGG_EDGE(IDX)                                                                  \
  {                                                                                    \
    const unsigned int v = *(const unsigned int*)(AB + (size_t)(IDX) * 256 + 128 + 2 * lane); \
    const float v0 = b2f((unsigned short)(v & 0xffffu));                               \
    const float v1 = b2f((unsigned short)(v >> 16));                                   \
    s0 += v0; q0 += v0 * v0; mn0 = fminf(mn0, v0); mx0 = fmaxf(mx0, v0);               \
    s1v += v1; q1 += v1 * v1; mn1 = fminf(mn1, v1); mx1 = fmaxf(mx1, v1);              \
  }

__global__ void aggregate_kernel(const unsigned short* __restrict__ AB,
                                 const unsigned short* __restrict__ hb,
                                 const float* __restrict__ b_pre,
                                 const int* __restrict__ rowptr, const int* __restrict__ ssrc,
                                 unsigned short* __restrict__ Xagg,
                                 float* __restrict__ sc1, float* __restrict__ sc2, int n) {
  const int node = blockIdx.x * 4 + (threadIdx.x >> 6);
  if (node >= n) return;
  const int lane = threadIdx.x & 63;
  const int beg = rowptr[node], end = rowptr[node + 1];
  const int cnt = end - beg;
  float s0 = 0.f, s1v = 0.f, q0 = 0.f, q1 = 0.f;
  float mn0 = 3.4e38f, mn1 = 3.4e38f, mx0 = -3.4e38f, mx1 = -3.4e38f;
  for (int base = beg; base < end; base += 64) {
    const int m = min(64, end - base);
    const int myidx = (base + lane < end) ? ssrc[base + lane] : 0;
    int t = 0;
    for (; t + 8 <= m; t += 8) {
      // 8 scalar indices (uniform lane arg -> SGPR), then 8 loads in flight, then math
      const int i0 = __builtin_amdgcn_readlane(myidx, t + 0);
      const int i1 = __builtin_amdgcn_readlane(myidx, t + 1);
      const int i2 = __builtin_amdgcn_readlane(myidx, t + 2);
      const int i3 = __builtin_amdgcn_readlane(myidx, t + 3);
      const int i4 = __builtin_amdgcn_readlane(myidx, t + 4);
      const int i5 = __builtin_amdgcn_readlane(myidx, t + 5);
      const int i6 = __builtin_amdgcn_readlane(myidx, t + 6);
      const int i7 = __builtin_amdgcn_readlane(myidx, t + 7);
      AGG_EDGE(i0) AGG_EDGE(i1) AGG_EDGE(i2) AGG_EDGE(i3)
      AGG_EDGE(i4) AGG_EDGE(i5) AGG_EDGE(i6) AGG_EDGE(i7)
    }
    for (; t < m; ++t) {
      const int i0 = __builtin_amdgcn_readlane(myidx, t);
      AGG_EDGE(i0)
    }
  }
  const float degf = (float)(cnt > 0 ? cnt : 1);
  const float2 bp = ((const float2*)b_pre)[lane];
  const unsigned int cpair = *(const unsigned int*)(AB + (size_t)node * 256 + 2 * lane);
  const float c0 = b2f((unsigned short)(cpair & 0xffffu)) + bp.x;
  const float c1 = b2f((unsigned short)(cpair >> 16)) + bp.y;
  float mean0, mean1, std0, std1, lo0, lo1, hi0, hi1;
  if (cnt > 0) {
    const float inv = 1.f / degf;
    const float mu0 = s0 * inv, mu1 = s1v * inv;
    mean0 = c0 + mu0; mean1 = c1 + mu1;
    std0 = sqrtf(fmaxf(q0 * inv - mu0 * mu0, 0.f) + 1e-5f);
    std1 = sqrtf(fmaxf(q1 * inv - mu1 * mu1, 0.f) + 1e-5f);
    lo0 = c0 + mn0; lo1 = c1 + mn1; hi0 = c0 + mx0; hi1 = c1 + mx1;
  } else {
    mean0 = mean1 = lo0 = lo1 = hi0 = hi1 = 0.f;
    std0 = std1 = sqrtf(1e-5f);
  }
  const float logd = logf(degf + 1.f);
  unsigned int* row = (unsigned int*)(Xagg + (size_t)node * 640);
  row[lane]       = *(const unsigned int*)(hb + (size_t)node * 128 + 2 * lane);
  row[64 + lane]  = pack2(mean0, mean1);
  row[128 + lane] = pack2(lo0, lo1);
  row[192 + lane] = pack2(hi0, hi1);
  row[256 + lane] = pack2(std0, std1);
  if (lane == 0) { sc1[node] = logd / AVG_LOG_F; sc2[node] = AVG_LOG_F / logd; }
}

// ---------- GEMM 2 (split): out3 = Xagg@W0 + diag(s1)*(Xagg[:,128:]@W1) + diag(s2)*(Xagg[:,128:]@W2) + bfold ----------
// W0 = WfoldT k in [0,640); W1 = [640,1152) vs A cols 128..640; W2 = [1152,1664) vs A cols 128..640.
// 512 threads = 8 waves (2 row x 4 col), wave tile 64x32, 3 accumulator sets.
__global__ __launch_bounds__(512) void gemm_split_kernel(
    const unsigned short* __restrict__ Xagg, const float* __restrict__ sc1,
    const float* __restrict__ sc2, const unsigned short* __restrict__ WT,
    const float* __restrict__ bias, float* __restrict__ out3, int M)
{
  constexpr int LDT = 40;  // 80B row stride: 16B-aligned, breaks pow2 bank aliasing
  constexpr int NK = 20;   // K=640 over A
  __shared__ alignas(16) unsigned short Asm[2][128 * LDT];
  __shared__ alignas(16) unsigned short B0s[2][128 * LDT];
  __shared__ alignas(16) unsigned short B1s[2][128 * LDT];
  __shared__ alignas(16) unsigned short B2s[2][128 * LDT];
  __shared__ float sLDS[2][128];
  const int tid = threadIdx.x, lane = tid & 63, w = tid >> 6;
  const int wr = w >> 2, wc = w & 3;  // 2 x 4 waves
  const int row0 = blockIdx.x * 128;
  const int srow = tid >> 2, slot = tid & 3;
  const int arow = min(row0 + srow, M - 1);
  const unsigned short* ap = Xagg + (size_t)arow * 640 + slot * 8;
  const unsigned short* bp = WT + (size_t)srow * 1664 + slot * 8;
  const int wa = srow * LDT + slot * 8;

  if (tid < 128) {
    const int rr = min(row0 + tid, M - 1);
    sLDS[0][tid] = sc1[rr];
    sLDS[1][tid] = sc2[rr];
  }

  int offA[4], offB[2];
#pragma unroll
  for (int i = 0; i < 4; ++i) offA[i] = (wr * 64 + i * 16 + (lane & 15)) * LDT + (lane >> 4) * 8;
#pragma unroll
  for (int i = 0; i < 2; ++i) offB[i] = (wc * 32 + i * 16 + (lane & 15)) * LDT + (lane >> 4) * 8;

  f32x4 acc0[4][2] = {}, acc1[4][2] = {}, acc2[4][2] = {};
  uint4 a = *(const uint4*)ap;
  uint4 b0 = *(const uint4*)bp;
  uint4 b1, b2;
  *(uint4*)&Asm[0][wa] = a;
  *(uint4*)&B0s[0][wa] = b0;
  __syncthreads();

  for (int kt = 0; kt < NK; ++kt) {
    const int cur = kt & 1;
    const bool pf = kt + 1 < NK;
    if (pf) {
      const int ka = (kt + 1) * 32;
      a = *(const uint4*)(ap + ka);
      b0 = *(const uint4*)(bp + ka);
      if (kt + 1 >= 4) {
        const int kb = ka - 128;
        b1 = *(const uint4*)(bp + 640 + kb);
        b2 = *(const uint4*)(bp + 1152 + kb);
      }
    }
    s16x8 af[4], q0[2];
#pragma unroll
    for (int i = 0; i < 4; ++i) af[i] = *(const s16x8*)&Asm[cur][offA[i]];
#pragma unroll
    for (int i = 0; i < 2; ++i) q0[i] = *(const s16x8*)&B0s[cur][offB[i]];
#pragma unroll
    for (int mi = 0; mi < 4; ++mi)
#pragma unroll
      for (int ni = 0; ni < 2; ++ni)
        acc0[mi][ni] = __builtin_amdgcn_mfma_f32_16x16x32_bf16(af[mi], q0[ni], acc0[mi][ni], 0, 0, 0);
    if (kt >= 4) {
      s16x8 q1[2], q2[2];
#pragma unroll
      for (int i = 0; i < 2; ++i) q1[i] = *(const s16x8*)&B1s[cur][offB[i]];
#pragma unroll
      for (int i = 0; i < 2; ++i) q2[i] = *(const s16x8*)&B2s[cur][offB[i]];
#pragma unroll
      for (int mi = 0; mi < 4; ++mi)
#pragma unroll
        for (int ni = 0; ni < 2; ++ni) {
          acc1[mi][ni] = __builtin_amdgcn_mfma_f32_16x16x32_bf16(af[mi], q1[ni], acc1[mi][ni], 0, 0, 0);
          acc2[mi][ni] = __builtin_amdgcn_mfma_f32_16x16x32_bf16(af[mi], q2[ni], acc2[mi][ni], 0, 0, 0);
        }
    }
    if (pf) {
      const int nxt = cur ^ 1;
      *(uint4*)&Asm[nxt][wa] = a;
      *(uint4*)&B0s[nxt][wa] = b0;
      if (kt + 1 >= 4) {
        *(uint4*)&B1s[nxt][wa] = b1;
        *(uint4*)&B2s[nxt][wa] = b2;
      }
      __syncthreads();
    }
  }

#pragma unroll
  for (int mi = 0; mi < 4; ++mi) {
#pragma unroll
    for (int ni = 0; ni < 2; ++ni) {
      const int rbase = row0 + wr * 64 + mi * 16 + (lane >> 4) * 4;
      const int c = wc * 32 + ni * 16 + (lane & 15);
      const float bb = bias[c];
#pragma unroll
      for (int r = 0; r < 4; ++r) {
        const int rr = rbase + r;
        if (rr < M) {
          const int rl = rr - row0;
          const float v = acc0[mi][ni][r] + sLDS[0][rl] * acc1[mi][ni][r]
                        + sLDS[1][rl] * acc2[mi][ni][r] + bb;
          out3[(size_t)rr * 128 + c] = v;
        }
      }
    }
  }
}

// ---------- BN stats ----------
__global__ void colreduce_kernel(const float* __restrict__ out3, float* __restrict__ bnsum, int n) {
  const int f = threadIdx.x;
  float s = 0.f, ss = 0.f;
  for (int r = blockIdx.x; r < n; r += gridDim.x) {
    const float v = out3[(size_t)r * 128 + f];
    s += v; ss += v * v;
  }
  atomicAdd(&bnsum[f], s);
  atomicAdd(&bnsum[128 + f], ss);
}

__global__ void bnfinal_kernel(const float* __restrict__ bnsum, const float* __restrict__ gamma,
                               const float* __restrict__ beta, float* __restrict__ sc,
                               float* __restrict__ shv, int n) {
  const int f = threadIdx.x;
  const float inv = 1.f / (float)n;
  const float mu = bnsum[f] * inv;
  const float var = bnsum[128 + f] * inv - mu * mu;
  const float rstd = rsqrtf(var + 1e-5f);
  const float s = gamma[f] * rstd;
  sc[f] = s;
  shv[f] = beta[f] - mu * s;
}

// ---------- BN apply + ReLU + residual ----------
__global__ void epilogue_kernel(const float* __restrict__ out3, const float* __restrict__ h,
                                const float* __restrict__ sc, const float* __restrict__ shv,
                                float* __restrict__ out, int total4) {
  int i = blockIdx.x * blockDim.x + threadIdx.x;
  if (i >= total4) return;
  const int c = (i & 31) * 4;
  const float4 x = ((const float4*)out3)[i];
  const float4 hh = ((const float4*)h)[i];
  float4 r;
  r.x = fmaxf(x.x * sc[c + 0] + shv[c + 0], 0.f) + hh.x;
  r.y = fmaxf(x.y * sc[c + 1] + shv[c + 1], 0.f) + hh.y;
  r.z = fmaxf(x.z * sc[c + 2] + shv[c + 2], 0.f) + hh.z;
  r.w = fmaxf(x.w * sc[c + 3] + shv[c + 3], 0.f) + hh.w;
  ((float4*)out)[i] = r;
}

extern "C" void kernel_launch(void* const* d_in, const int* in_sizes, int n_in,
                              void* d_out, int out_size, void* d_ws, size_t ws_size,
                              hipStream_t stream) {
  const float* h      = (const float*)d_in[0];
  const int*   ei     = (const int*)d_in[1];
  const float* W_pre  = (const float*)d_in[2];
  const float* b_pre  = (const float*)d_in[3];
  const float* W_post = (const float*)d_in[4];
  const float* b_post = (const float*)d_in[5];
  const float* W_lin  = (const float*)d_in[6];
  const float* b_lin  = (const float*)d_in[7];
  const float* gamma  = (const float*)d_in[8];
  const float* beta   = (const float*)d_in[9];

  const int n = in_sizes[0] / 128;
  const int E = in_sizes[1] / 2;
  const int* src = ei;
  const int* dst = ei + E;

  char* ws = (char*)d_ws;
  size_t off = 0;
  auto carve = [&](size_t bytes) {
    off = (off + 255) & ~(size_t)255;
    void* p = ws + off;
    off += bytes;
    return p;
  };
  unsigned short* hb   = (unsigned short*)carve((size_t)n * 128 * 2);
  void* ab_out3        = carve((size_t)n * 256 * 2);  // AB (bf16) then reused as out3 (f32)
  unsigned short* AB   = (unsigned short*)ab_out3;
  float* out3          = (float*)ab_out3;
  unsigned short* Xagg = (unsigned short*)carve((size_t)n * 640 * 2);
  float* sc1           = (float*)carve((size_t)n * 4);
  float* sc2           = (float*)carve((size_t)n * 4);
  unsigned short* WcatT  = (unsigned short*)carve(256 * 128 * 2);
  unsigned short* WfoldT = (unsigned short*)carve((size_t)128 * 1664 * 2);
  float* bfold         = (float*)carve(128 * 4);
  int*   cnt           = (int*)carve((size_t)n * 4);
  int*   rowptr        = (int*)carve((size_t)(n + 1) * 4);
  int*   cursor        = (int*)carve((size_t)n * 4);
  int*   ssrc          = (int*)carve((size_t)E * 4);
  int*   bsum          = (int*)carve((size_t)256 * 4);
  float* bnsum         = (float*)carve(256 * 4);
  float* bnsc          = (float*)carve(128 * 4);
  float* bnsh          = (float*)carve(128 * 4);

  const int total4 = n * 128 / 4;
  const int mt = (n + 127) / 128;
  const int nb = (n + 255) / 256;

  conv_h_kernel<<<(total4 + 255) / 256, 256, 0, stream>>>(h, hb, total4);
  fold_wcat_kernel<<<128, 256, 0, stream>>>(W_pre, WcatT);
  fold_wpost_kernel<<<209, 128, 0, stream>>>(W_post, b_post, W_lin, b_lin, WfoldT, bfold);

  hipMemsetAsync(cnt, 0, (size_t)n * 4, stream);
  hist_kernel<<<(E + 255) / 256, 256, 0, stream>>>(dst, cnt, E);
  scan1_kernel<<<nb, 256, 0, stream>>>(cnt, bsum, n);
  scan2_kernel<<<1, 256, 0, stream>>>(bsum, rowptr, n, nb);
  scan3_kernel<<<nb, 256, 0, stream>>>(cnt, bsum, rowptr, cursor, n);
  scatter_kernel<<<(E + 255) / 256, 256, 0, stream>>>(src, dst, cursor, ssrc, E);

  gemm256_kernel<<<dim3(mt, 2), 256, 0, stream>>>(hb, WcatT, AB, n);
  aggregate_kernel<<<(n + 3) / 4, 256, 0, stream>>>(AB, hb, b_pre, rowptr, ssrc, Xagg, sc1, sc2, n);
  gemm_split_kernel<<<mt, 512, 0, stream>>>(Xagg, sc1, sc2, WfoldT, bfold, out3, n);

  hipMemsetAsync(bnsum, 0, 256 * 4, stream);
  colreduce_kernel<<<512, 128, 0, stream>>>(out3, bnsum, n);
  bnfinal_kernel<<<1, 128, 0, stream>>>(bnsum, gamma, beta, bnsc, bnsh, n);
  epilogue_kernel<<<(total4 + 255) / 256, 256, 0, stream>>>(out3, h, bnsc, bnsh, (float*)d_out, total4);
}

// Round 6
// 291.156 us; speedup vs baseline: 1.6834x; 1.2575x over previous
//
#include <hip/hip_runtime.h>
#include <hip/hip_bf16.h>
#include <cstdint>
#include <cstddef>

typedef short s16x8 __attribute__((ext_vector_type(8)));
typedef float f32x4 __attribute__((ext_vector_type(4)));

#define AVG_LOG_F 2.8332133f  // ln(17)

static __device__ __forceinline__ float b2f(unsigned short u) {
  union { unsigned int i; float f; } x; x.i = ((unsigned int)u) << 16; return x.f;
}
static __device__ __forceinline__ unsigned short f2b(float f) {
  __hip_bfloat16 h = __float2bfloat16(f);
  union { __hip_bfloat16 hh; unsigned short u; } c; c.hh = h; return c.u;
}
static __device__ __forceinline__ unsigned int pack2(float lo, float hi) {
  return (unsigned int)f2b(lo) | ((unsigned int)f2b(hi) << 16);
}

// ---------- h fp32 -> bf16 ----------
__global__ void conv_h_kernel(const float* __restrict__ h, unsigned short* __restrict__ hb, int total4) {
  int i = blockIdx.x * blockDim.x + threadIdx.x;
  if (i >= total4) return;
  const float4 v = ((const float4*)h)[i];
  uint2 r;
  r.x = pack2(v.x, v.y);
  r.y = pack2(v.z, v.w);
  ((uint2*)hb)[i] = r;
}

// ---------- WcatT[c][k] ----------
__global__ void fold_wcat_kernel(const float* __restrict__ W_pre, unsigned short* __restrict__ WcatT) {
  int idx = blockIdx.x * blockDim.x + threadIdx.x;
  int c = idx >> 7, k = idx & 127;
  float v = (c < 128) ? W_pre[k * 128 + c] : W_pre[(128 + k) * 128 + (c - 128)];
  WcatT[c * 128 + k] = f2b(v);
}

// ---------- WfoldT = (W_post @ W_lin)^T ; block 208 computes bfold ----------
__global__ __launch_bounds__(128) void fold_wpost_kernel(
    const float* __restrict__ W_post, const float* __restrict__ b_post,
    const float* __restrict__ W_lin, const float* __restrict__ b_lin,
    unsigned short* __restrict__ WfoldT, float* __restrict__ bfold) {
  __shared__ float wl[128 * 128];
  const int j = threadIdx.x;
  for (int r = 0; r < 128; ++r) wl[r * 128 + j] = W_lin[r * 128 + j];
  __syncthreads();
  if (blockIdx.x == 208) {
    float acc = b_lin[j];
    for (int k = 0; k < 128; ++k) acc += b_post[k] * wl[k * 128 + j];
    bfold[j] = acc;
  } else {
#pragma unroll 2
    for (int ii = 0; ii < 8; ++ii) {
      const int i = blockIdx.x * 8 + ii;
      float acc = 0.f;
      for (int k = 0; k < 128; ++k) acc += W_post[i * 128 + k] * wl[k * 128 + j];
      WfoldT[(size_t)j * 1664 + i] = f2b(acc);
    }
  }
}

// ================= bucketed CSR build (write-amplification-free) =================
// bucket b = dst >> 8 (256 nodes per bucket); record = ((dst&255)<<16) | src  (src < 65536)

// ---- bucket histogram, LDS pre-reduced ----
__global__ void bucket_hist_kernel(const int* __restrict__ dst, int* __restrict__ bucketCnt, int E) {
  __shared__ int lcnt[256];
  const int tid = threadIdx.x;
  lcnt[tid] = 0;
  __syncthreads();
  for (int e = blockIdx.x * 256 + tid; e < E; e += gridDim.x * 256)
    atomicAdd(&lcnt[dst[e] >> 8], 1);
  __syncthreads();
  if (lcnt[tid] > 0) atomicAdd(&bucketCnt[tid], lcnt[tid]);
}

// ---- exclusive scan of bucket counts -> base & cursor; rowptr[n] = E ----
__global__ void bucket_scan_kernel(const int* __restrict__ bucketCnt, int* __restrict__ bucketBase,
                                   int* __restrict__ bucketCursor, int* __restrict__ rowptr,
                                   int n, int nb, int E) {
  __shared__ int sh[256];
  const int tid = threadIdx.x;
  const int v = (tid < nb) ? bucketCnt[tid] : 0;
  sh[tid] = v;
  __syncthreads();
  for (int o = 1; o < 256; o <<= 1) {
    int t = (tid >= o) ? sh[tid - o] : 0;
    __syncthreads();
    sh[tid] += t;
    __syncthreads();
  }
  const int base = sh[tid] - v;  // exclusive
  if (tid < nb) { bucketBase[tid] = base; bucketCursor[tid] = base; }
  if (tid == nb - 1) bucketBase[nb] = base + v;
  if (tid == 0) rowptr[n] = E;
}

// ---- chunked LDS-staged scatter into bucket segments ----
__global__ __launch_bounds__(256) void s1_scatter_kernel(
    const int* __restrict__ src, const int* __restrict__ dst,
    int* __restrict__ bucketCursor, unsigned int* __restrict__ bucketed, int E, int CH) {
  __shared__ int lcnt[256], loff[256], lcur[256], gbase[256];
  __shared__ unsigned int stage[5000];
  __shared__ unsigned char sbid[5000];
  const int tid = threadIdx.x;
  const int c0 = blockIdx.x * CH;
  const int c1 = min(c0 + CH, E);
  const int cnt = c1 - c0;
  if (cnt <= 0) return;
  lcnt[tid] = 0;
  __syncthreads();
  for (int e = c0 + tid; e < c1; e += 256) atomicAdd(&lcnt[dst[e] >> 8], 1);
  __syncthreads();
  const int v = lcnt[tid];
  loff[tid] = 0;
  __syncthreads();
  {
    __shared__ int tmp[256];
    tmp[tid] = v;
    __syncthreads();
    for (int o = 1; o < 256; o <<= 1) {
      int t = (tid >= o) ? tmp[tid - o] : 0;
      __syncthreads();
      tmp[tid] += t;
      __syncthreads();
    }
    loff[tid] = tmp[tid] - v;  // exclusive
  }
  lcur[tid] = loff[tid];
  gbase[tid] = (v > 0) ? atomicAdd(&bucketCursor[tid], v) : 0;
  __syncthreads();
  // place into LDS staging (bucket-grouped)
  for (int e = c0 + tid; e < c1; e += 256) {
    const int d = dst[e];
    const int b = d >> 8;
    const int slot = atomicAdd(&lcur[b], 1);
    stage[slot] = ((unsigned int)(d & 255) << 16) | (unsigned int)src[e];
    sbid[slot] = (unsigned char)b;
  }
  __syncthreads();
  // flush: contiguous runs per bucket
  for (int i = tid; i < cnt; i += 256) {
    const int b = sbid[i];
    bucketed[gbase[b] + (i - loff[b])] = stage[i];
  }
}

// ---- per-bucket: node counts -> rowptr; place src16 -> ssrc (coalesced, single-writer) ----
__global__ __launch_bounds__(256) void s2_build_kernel(
    const unsigned int* __restrict__ bucketed, const int* __restrict__ bucketBase,
    int* __restrict__ rowptr, unsigned short* __restrict__ ssrc, int n) {
  __shared__ int ncnt[256], noff[256], ncur[256];
  __shared__ unsigned short csr16[8192];
  const int tid = threadIdx.x;
  const int b = blockIdx.x;
  const int seg0 = bucketBase[b], seg1 = bucketBase[b + 1];
  const int cnt = seg1 - seg0;
  ncnt[tid] = 0;
  __syncthreads();
  for (int i = tid; i < cnt; i += 256) atomicAdd(&ncnt[bucketed[seg0 + i] >> 16], 1);
  __syncthreads();
  const int v = ncnt[tid];
  {
    __shared__ int tmp[256];
    tmp[tid] = v;
    __syncthreads();
    for (int o = 1; o < 256; o <<= 1) {
      int t = (tid >= o) ? tmp[tid - o] : 0;
      __syncthreads();
      tmp[tid] += t;
      __syncthreads();
    }
    noff[tid] = tmp[tid] - v;
  }
  ncur[tid] = noff[tid];
  const int node = (b << 8) + tid;
  if (node < n) rowptr[node] = seg0 + noff[tid];
  __syncthreads();
  for (int i = tid; i < cnt; i += 256) {
    const unsigned int rec = bucketed[seg0 + i];
    const int d = rec >> 16;
    const int slot = atomicAdd(&ncur[d], 1);
    if (slot < 8192) csr16[slot] = (unsigned short)(rec & 0xffffu);
  }
  __syncthreads();
  for (int i = tid; i < cnt; i += 256) ssrc[seg0 + i] = csr16[i];
}

// ---------- GEMM 1: AB[M,256] = hb[M,128] @ WcatT[256,128]^T, bf16 out ----------
__global__ __launch_bounds__(256) void gemm256_kernel(
    const unsigned short* __restrict__ A, const unsigned short* __restrict__ BT,
    unsigned short* __restrict__ outb, int M)
{
  constexpr int LDT = 40;
  constexpr int K = 128, NK = K / 32;
  __shared__ alignas(16) unsigned short Asm[2][128 * LDT];
  __shared__ alignas(16) unsigned short Bsm[2][128 * LDT];
  const int tid = threadIdx.x, lane = tid & 63;
  const int w = tid >> 6, wr = w >> 1, wc = w & 1;
  const int row0 = blockIdx.x * 128;
  const int col0 = blockIdx.y * 128;
  const int srow = tid >> 2, slot = tid & 3;
  const int ar0 = min(row0 + srow, M - 1);
  const int ar1 = min(row0 + srow + 64, M - 1);
  const unsigned short* ap0 = A + (size_t)ar0 * K + slot * 8;
  const unsigned short* ap1 = A + (size_t)ar1 * K + slot * 8;
  const unsigned short* bp0 = BT + (size_t)(col0 + srow) * K + slot * 8;
  const unsigned short* bp1 = BT + (size_t)(col0 + srow + 64) * K + slot * 8;
  const int wa0 = srow * LDT + slot * 8, wa1 = wa0 + 64 * LDT;

  int offA[4], offB[4];
#pragma unroll
  for (int i = 0; i < 4; ++i) {
    offA[i] = (wr * 64 + i * 16 + (lane & 15)) * LDT + (lane >> 4) * 8;
    offB[i] = (wc * 64 + i * 16 + (lane & 15)) * LDT + (lane >> 4) * 8;
  }

  f32x4 acc[4][4] = {};
  uint4 a0 = *(const uint4*)ap0;
  uint4 a1 = *(const uint4*)ap1;
  uint4 b0 = *(const uint4*)bp0;
  uint4 b1 = *(const uint4*)bp1;
  *(uint4*)&Asm[0][wa0] = a0; *(uint4*)&Asm[0][wa1] = a1;
  *(uint4*)&Bsm[0][wa0] = b0; *(uint4*)&Bsm[0][wa1] = b1;
  __syncthreads();

  for (int kt = 0; kt < NK; ++kt) {
    const int cur = kt & 1;
    if (kt + 1 < NK) {
      const int k0 = (kt + 1) * 32;
      a0 = *(const uint4*)(ap0 + k0); a1 = *(const uint4*)(ap1 + k0);
      b0 = *(const uint4*)(bp0 + k0); b1 = *(const uint4*)(bp1 + k0);
    }
    s16x8 af[4], bq[4];
#pragma unroll
    for (int i = 0; i < 4; ++i) af[i] = *(const s16x8*)&Asm[cur][offA[i]];
#pragma unroll
    for (int i = 0; i < 4; ++i) bq[i] = *(const s16x8*)&Bsm[cur][offB[i]];
#pragma unroll
    for (int mi = 0; mi < 4; ++mi)
#pragma unroll
      for (int ni = 0; ni < 4; ++ni)
        acc[mi][ni] = __builtin_amdgcn_mfma_f32_16x16x32_bf16(af[mi], bq[ni], acc[mi][ni], 0, 0, 0);
    if (kt + 1 < NK) {
      const int nxt = cur ^ 1;
      *(uint4*)&Asm[nxt][wa0] = a0; *(uint4*)&Asm[nxt][wa1] = a1;
      *(uint4*)&Bsm[nxt][wa0] = b0; *(uint4*)&Bsm[nxt][wa1] = b1;
      __syncthreads();
    }
  }

#pragma unroll
  for (int mi = 0; mi < 4; ++mi) {
#pragma unroll
    for (int ni = 0; ni < 4; ++ni) {
      const int rbase = row0 + wr * 64 + mi * 16 + (lane >> 4) * 4;
      const int c = col0 + wc * 64 + ni * 16 + (lane & 15);
#pragma unroll
      for (int r = 0; r < 4; ++r) {
        const int rr = rbase + r;
        if (rr < M) outb[(size_t)rr * 256 + c] = f2b(acc[mi][ni][r]);
      }
    }
  }
}

// ---------- per-node aggregation (wave per node, readlane-batched gathers) ----------
#define AGG_EDGE(IDX)                                                                  \
  {                                                                                    \
    const unsigned int v = *(const unsigned int*)(AB + (size_t)(IDX) * 256 + 128 + 2 * lane); \
    const float v0 = b2f((unsigned short)(v & 0xffffu));                               \
    const float v1 = b2f((unsigned short)(v >> 16));                                   \
    s0 += v0; q0 += v0 * v0; mn0 = fminf(mn0, v0); mx0 = fmaxf(mx0, v0);               \
    s1v += v1; q1 += v1 * v1; mn1 = fminf(mn1, v1); mx1 = fmaxf(mx1, v1);              \
  }

__global__ void aggregate_kernel(const unsigned short* __restrict__ AB,
                                 const unsigned short* __restrict__ hb,
                                 const float* __restrict__ b_pre,
                                 const int* __restrict__ rowptr, const unsigned short* __restrict__ ssrc,
                                 unsigned short* __restrict__ Xagg,
                                 float* __restrict__ sc1, float* __restrict__ sc2, int n) {
  const int node = blockIdx.x * 4 + (threadIdx.x >> 6);
  if (node >= n) return;
  const int lane = threadIdx.x & 63;
  const int beg = rowptr[node], end = rowptr[node + 1];
  const int cnt = end - beg;
  float s0 = 0.f, s1v = 0.f, q0 = 0.f, q1 = 0.f;
  float mn0 = 3.4e38f, mn1 = 3.4e38f, mx0 = -3.4e38f, mx1 = -3.4e38f;
  for (int base = beg; base < end; base += 64) {
    const int m = min(64, end - base);
    const int myidx = (base + lane < end) ? (int)ssrc[base + lane] : 0;
    int t = 0;
    for (; t + 8 <= m; t += 8) {
      const int i0 = __builtin_amdgcn_readlane(myidx, t + 0);
      const int i1 = __builtin_amdgcn_readlane(myidx, t + 1);
      const int i2 = __builtin_amdgcn_readlane(myidx, t + 2);
      const int i3 = __builtin_amdgcn_readlane(myidx, t + 3);
      const int i4 = __builtin_amdgcn_readlane(myidx, t + 4);
      const int i5 = __builtin_amdgcn_readlane(myidx, t + 5);
      const int i6 = __builtin_amdgcn_readlane(myidx, t + 6);
      const int i7 = __builtin_amdgcn_readlane(myidx, t + 7);
      AGG_EDGE(i0) AGG_EDGE(i1) AGG_EDGE(i2) AGG_EDGE(i3)
      AGG_EDGE(i4) AGG_EDGE(i5) AGG_EDGE(i6) AGG_EDGE(i7)
    }
    for (; t < m; ++t) {
      const int i0 = __builtin_amdgcn_readlane(myidx, t);
      AGG_EDGE(i0)
    }
  }
  const float degf = (float)(cnt > 0 ? cnt : 1);
  const float2 bp = ((const float2*)b_pre)[lane];
  const unsigned int cpair = *(const unsigned int*)(AB + (size_t)node * 256 + 2 * lane);
  const float c0 = b2f((unsigned short)(cpair & 0xffffu)) + bp.x;
  const float c1 = b2f((unsigned short)(cpair >> 16)) + bp.y;
  float mean0, mean1, std0, std1, lo0, lo1, hi0, hi1;
  if (cnt > 0) {
    const float inv = 1.f / degf;
    const float mu0 = s0 * inv, mu1 = s1v * inv;
    mean0 = c0 + mu0; mean1 = c1 + mu1;
    std0 = sqrtf(fmaxf(q0 * inv - mu0 * mu0, 0.f) + 1e-5f);
    std1 = sqrtf(fmaxf(q1 * inv - mu1 * mu1, 0.f) + 1e-5f);
    lo0 = c0 + mn0; lo1 = c1 + mn1; hi0 = c0 + mx0; hi1 = c1 + mx1;
  } else {
    mean0 = mean1 = lo0 = lo1 = hi0 = hi1 = 0.f;
    std0 = std1 = sqrtf(1e-5f);
  }
  const float logd = logf(degf + 1.f);
  unsigned int* row = (unsigned int*)(Xagg + (size_t)node * 640);
  row[lane]       = *(const unsigned int*)(hb + (size_t)node * 128 + 2 * lane);
  row[64 + lane]  = pack2(mean0, mean1);
  row[128 + lane] = pack2(lo0, lo1);
  row[192 + lane] = pack2(hi0, hi1);
  row[256 + lane] = pack2(std0, std1);
  if (lane == 0) { sc1[node] = logd / AVG_LOG_F; sc2[node] = AVG_LOG_F / logd; }
}

// ---------- GEMM 2 (split) + fused BN column partial sums ----------
__global__ __launch_bounds__(512) void gemm_split_kernel(
    const unsigned short* __restrict__ Xagg, const float* __restrict__ sc1,
    const float* __restrict__ sc2, const unsigned short* __restrict__ WT,
    const float* __restrict__ bias, float* __restrict__ out3,
    float* __restrict__ bnsum, int M)
{
  constexpr int LDT = 40;
  constexpr int NK = 20;
  __shared__ alignas(16) unsigned short Asm[2][128 * LDT];
  __shared__ alignas(16) unsigned short B0s[2][128 * LDT];
  __shared__ alignas(16) unsigned short B1s[2][128 * LDT];
  __shared__ alignas(16) unsigned short B2s[2][128 * LDT];
  __shared__ float sLDS[2][128];
  __shared__ float bnacc[256];
  const int tid = threadIdx.x, lane = tid & 63, w = tid >> 6;
  const int wr = w >> 2, wc = w & 3;
  const int row0 = blockIdx.x * 128;
  const int srow = tid >> 2, slot = tid & 3;
  const int arow = min(row0 + srow, M - 1);
  const unsigned short* ap = Xagg + (size_t)arow * 640 + slot * 8;
  const unsigned short* bp = WT + (size_t)srow * 1664 + slot * 8;
  const int wa = srow * LDT + slot * 8;

  if (tid < 128) {
    const int rr = min(row0 + tid, M - 1);
    sLDS[0][tid] = sc1[rr];
    sLDS[1][tid] = sc2[rr];
  }
  if (tid < 256) bnacc[tid] = 0.f;

  int offA[4], offB[2];
#pragma unroll
  for (int i = 0; i < 4; ++i) offA[i] = (wr * 64 + i * 16 + (lane & 15)) * LDT + (lane >> 4) * 8;
#pragma unroll
  for (int i = 0; i < 2; ++i) offB[i] = (wc * 32 + i * 16 + (lane & 15)) * LDT + (lane >> 4) * 8;

  f32x4 acc0[4][2] = {}, acc1[4][2] = {}, acc2[4][2] = {};
  uint4 a = *(const uint4*)ap;
  uint4 b0 = *(const uint4*)bp;
  uint4 b1, b2;
  *(uint4*)&Asm[0][wa] = a;
  *(uint4*)&B0s[0][wa] = b0;
  __syncthreads();

  for (int kt = 0; kt < NK; ++kt) {
    const int cur = kt & 1;
    const bool pf = kt + 1 < NK;
    if (pf) {
      const int ka = (kt + 1) * 32;
      a = *(const uint4*)(ap + ka);
      b0 = *(const uint4*)(bp + ka);
      if (kt + 1 >= 4) {
        const int kb = ka - 128;
        b1 = *(const uint4*)(bp + 640 + kb);
        b2 = *(const uint4*)(bp + 1152 + kb);
      }
    }
    s16x8 af[4], q0[2];
#pragma unroll
    for (int i = 0; i < 4; ++i) af[i] = *(const s16x8*)&Asm[cur][offA[i]];
#pragma unroll
    for (int i = 0; i < 2; ++i) q0[i] = *(const s16x8*)&B0s[cur][offB[i]];
#pragma unroll
    for (int mi = 0; mi < 4; ++mi)
#pragma unroll
      for (int ni = 0; ni < 2; ++ni)
        acc0[mi][ni] = __builtin_amdgcn_mfma_f32_16x16x32_bf16(af[mi], q0[ni], acc0[mi][ni], 0, 0, 0);
    if (kt >= 4) {
      s16x8 q1[2], q2[2];
#pragma unroll
      for (int i = 0; i < 2; ++i) q1[i] = *(const s16x8*)&B1s[cur][offB[i]];
#pragma unroll
      for (int i = 0; i < 2; ++i) q2[i] = *(const s16x8*)&B2s[cur][offB[i]];
#pragma unroll
      for (int mi = 0; mi < 4; ++mi)
#pragma unroll
        for (int ni = 0; ni < 2; ++ni) {
          acc1[mi][ni] = __builtin_amdgcn_mfma_f32_16x16x32_bf16(af[mi], q1[ni], acc1[mi][ni], 0, 0, 0);
          acc2[mi][ni] = __builtin_amdgcn_mfma_f32_16x16x32_bf16(af[mi], q2[ni], acc2[mi][ni], 0, 0, 0);
        }
    }
    if (pf) {
      const int nxt = cur ^ 1;
      *(uint4*)&Asm[nxt][wa] = a;
      *(uint4*)&B0s[nxt][wa] = b0;
      if (kt + 1 >= 4) {
        *(uint4*)&B1s[nxt][wa] = b1;
        *(uint4*)&B2s[nxt][wa] = b2;
      }
      __syncthreads();
    }
  }

  float cs[2] = {0.f, 0.f}, css[2] = {0.f, 0.f};
#pragma unroll
  for (int mi = 0; mi < 4; ++mi) {
#pragma unroll
    for (int ni = 0; ni < 2; ++ni) {
      const int rbase = row0 + wr * 64 + mi * 16 + (lane >> 4) * 4;
      const int c = wc * 32 + ni * 16 + (lane & 15);
      const float bb = bias[c];
#pragma unroll
      for (int r = 0; r < 4; ++r) {
        const int rr = rbase + r;
        if (rr < M) {
          const int rl = rr - row0;
          const float v = acc0[mi][ni][r] + sLDS[0][rl] * acc1[mi][ni][r]
                        + sLDS[1][rl] * acc2[mi][ni][r] + bb;
          out3[(size_t)rr * 128 + c] = v;
          cs[ni] += v; css[ni] += v * v;
        }
      }
    }
  }
  __syncthreads();  // all K-loop LDS traffic done; bnacc stable since init
#pragma unroll
  for (int ni = 0; ni < 2; ++ni) {
    const int c = wc * 32 + ni * 16 + (lane & 15);
    atomicAdd(&bnacc[c], cs[ni]);
    atomicAdd(&bnacc[128 + c], css[ni]);
  }
  __syncthreads();
  if (tid < 128) {
    atomicAdd(&bnsum[tid], bnacc[tid]);
    atomicAdd(&bnsum[128 + tid], bnacc[128 + tid]);
  }
}

// ---------- BN finalize ----------
__global__ void bnfinal_kernel(const float* __restrict__ bnsum, const float* __restrict__ gamma,
                               const float* __restrict__ beta, float* __restrict__ sc,
                               float* __restrict__ shv, int n) {
  const int f = threadIdx.x;
  const float inv = 1.f / (float)n;
  const float mu = bnsum[f] * inv;
  const float var = bnsum[128 + f] * inv - mu * mu;
  const float rstd = rsqrtf(var + 1e-5f);
  const float s = gamma[f] * rstd;
  sc[f] = s;
  shv[f] = beta[f] - mu * s;
}

// ---------- BN apply + ReLU + residual ----------
__global__ void epilogue_kernel(const float* __restrict__ out3, const float* __restrict__ h,
                                const float* __restrict__ sc, const float* __restrict__ shv,
                                float* __restrict__ out, int total4) {
  int i = blockIdx.x * blockDim.x + threadIdx.x;
  if (i >= total4) return;
  const int c = (i & 31) * 4;
  const float4 x = ((const float4*)out3)[i];
  const float4 hh = ((const float4*)h)[i];
  float4 r;
  r.x = fmaxf(x.x * sc[c + 0] + shv[c + 0], 0.f) + hh.x;
  r.y = fmaxf(x.y * sc[c + 1] + shv[c + 1], 0.f) + hh.y;
  r.z = fmaxf(x.z * sc[c + 2] + shv[c + 2], 0.f) + hh.z;
  r.w = fmaxf(x.w * sc[c + 3] + shv[c + 3], 0.f) + hh.w;
  ((float4*)out)[i] = r;
}

extern "C" void kernel_launch(void* const* d_in, const int* in_sizes, int n_in,
                              void* d_out, int out_size, void* d_ws, size_t ws_size,
                              hipStream_t stream) {
  const float* h      = (const float*)d_in[0];
  const int*   ei     = (const int*)d_in[1];
  const float* W_pre  = (const float*)d_in[2];
  const float* b_pre  = (const float*)d_in[3];
  const float* W_post = (const float*)d_in[4];
  const float* b_post = (const float*)d_in[5];
  const float* W_lin  = (const float*)d_in[6];
  const float* b_lin  = (const float*)d_in[7];
  const float* gamma  = (const float*)d_in[8];
  const float* beta   = (const float*)d_in[9];

  const int n = in_sizes[0] / 128;
  const int E = in_sizes[1] / 2;
  const int* src = ei;
  const int* dst = ei + E;

  char* ws = (char*)d_ws;
  size_t off = 0;
  auto carve = [&](size_t bytes) {
    off = (off + 255) & ~(size_t)255;
    void* p = ws + off;
    off += bytes;
    return p;
  };
  unsigned short* hb   = (unsigned short*)carve((size_t)n * 128 * 2);
  void* ab_out3        = carve((size_t)n * 256 * 2);  // AB (bf16) then reused as out3 (f32)
  unsigned short* AB   = (unsigned short*)ab_out3;
  float* out3          = (float*)ab_out3;
  unsigned short* Xagg = (unsigned short*)carve((size_t)n * 640 * 2);
  float* sc1           = (float*)carve((size_t)n * 4);
  float* sc2           = (float*)carve((size_t)n * 4);
  unsigned short* WcatT  = (unsigned short*)carve(256 * 128 * 2);
  unsigned short* WfoldT = (unsigned short*)carve((size_t)128 * 1664 * 2);
  float* bfold         = (float*)carve(128 * 4);
  int*   bucketCnt     = (int*)carve(256 * 4);
  int*   bucketBase    = (int*)carve(257 * 4);
  int*   bucketCursor  = (int*)carve(256 * 4);
  unsigned int* bucketed = (unsigned int*)carve((size_t)E * 4);
  int*   rowptr        = (int*)carve((size_t)(n + 1) * 4);
  unsigned short* ssrc = (unsigned short*)carve((size_t)(E + 2) * 2);
  float* bnsum         = (float*)carve(256 * 4);
  float* bnsc          = (float*)carve(128 * 4);
  float* bnsh          = (float*)carve(128 * 4);

  const int total4 = n * 128 / 4;
  const int mt = (n + 127) / 128;
  const int nb = (n + 255) >> 8;             // buckets of 256 nodes (needs n <= 65536)
  const int nS1 = (E + 4999) / 5000;         // chunk <= 5000 (LDS staging cap)

  conv_h_kernel<<<(total4 + 255) / 256, 256, 0, stream>>>(h, hb, total4);
  fold_wcat_kernel<<<128, 256, 0, stream>>>(W_pre, WcatT);
  fold_wpost_kernel<<<209, 128, 0, stream>>>(W_post, b_post, W_lin, b_lin, WfoldT, bfold);

  hipMemsetAsync(bucketCnt, 0, 256 * 4, stream);
  hipMemsetAsync(bnsum, 0, 256 * 4, stream);
  bucket_hist_kernel<<<256, 256, 0, stream>>>(dst, bucketCnt, E);
  bucket_scan_kernel<<<1, 256, 0, stream>>>(bucketCnt, bucketBase, bucketCursor, rowptr, n, nb, E);
  s1_scatter_kernel<<<nS1, 256, 0, stream>>>(src, dst, bucketCursor, bucketed, E, 5000);
  s2_build_kernel<<<nb, 256, 0, stream>>>(bucketed, bucketBase, rowptr, ssrc, n);

  gemm256_kernel<<<dim3(mt, 2), 256, 0, stream>>>(hb, WcatT, AB, n);
  aggregate_kernel<<<(n + 3) / 4, 256, 0, stream>>>(AB, hb, b_pre, rowptr, ssrc, Xagg, sc1, sc2, n);
  gemm_split_kernel<<<mt, 512, 0, stream>>>(Xagg, sc1, sc2, WfoldT, bfold, out3, bnsum, n);

  bnfinal_kernel<<<1, 128, 0, stream>>>(bnsum, gamma, beta, bnsc, bnsh, n);
  epilogue_kernel<<<(total4 + 255) / 256, 256, 0, stream>>>(out3, h, bnsc, bnsh, (float*)d_out, total4);
}